// Round 1
// baseline (2322.016 us; speedup 1.0000x reference)
//
#include <hip/hip_runtime.h>
#include <hip/hip_bf16.h>

#define DIM 256
#define HEADS 8
#define DHEAD 64
#define GSLICE 64
#define INNER 512
#define NPTS 32768

typedef unsigned int uint32;

static __device__ __forceinline__ unsigned short f2bf(float f) {
    unsigned int u = __float_as_uint(f);
    u += 0x7fffu + ((u >> 16) & 1u);   // round-to-nearest-even
    return (unsigned short)(u >> 16);
}
static __device__ __forceinline__ float bflo(uint32 v) {
    return __uint_as_float(v << 16);
}
static __device__ __forceinline__ float bfhi(uint32 v) {
    return __uint_as_float(v & 0xffff0000u);
}

// ---------------------------------------------------------------------------
// K1: fused projection GEMM + slice softmax.
// grid.x = Mtotal/64 row tiles, grid.y = 16 column tiles (0..7 -> fx head h,
// 8..15 -> x_mid head h-8 with fused logits+softmax -> w).
// ---------------------------------------------------------------------------
__global__ __launch_bounds__(256) void k_proj(
    const float* __restrict__ x,
    const float* __restrict__ Wfx, const float* __restrict__ bfx,
    const float* __restrict__ Wx,  const float* __restrict__ bx,
    const float* __restrict__ Wsl, const float* __restrict__ bsl,
    const float* __restrict__ temp,
    unsigned short* __restrict__ fx_out,   // bf16 bits, (Mtotal, 512)
    unsigned short* __restrict__ w_out)    // bf16 bits, (Mtotal, 512) [h*64+g]
{
    const int mtile = blockIdx.x;
    const int ntile = blockIdx.y;
    const bool is_fx = (ntile < HEADS);
    const int h = is_fx ? ntile : (ntile - HEADS);
    const int col0 = h * 64;
    const float* __restrict__ W = is_fx ? Wfx : Wx;

    __shared__ float As[16][68];     // transposed A tile [k][m], padded
    __shared__ float Bs[16][64];     // [k][n]
    __shared__ float xm[64][65];     // x_mid tile for softmax phase
    __shared__ float WslS[64][64];   // W_slice staged

    const int t  = threadIdx.x;
    const int ty = t >> 4, tx = t & 15;
    const int lm = t >> 2, lk = (t & 3) * 4;    // A-load mapping
    const int bk = t >> 4, bn = (t & 15) * 4;   // B-load mapping

    if (!is_fx) {
        for (int i = t; i < 64 * 64; i += 256) WslS[i >> 6][i & 63] = Wsl[i];
    }

    float acc[4][4] = {};
    const float* Arow = x + (size_t)mtile * 64 * DIM;

    for (int kb = 0; kb < DIM; kb += 16) {
        float4 av = *(const float4*)(Arow + (size_t)lm * DIM + kb + lk);
        float4 bv = *(const float4*)(W + (size_t)(kb + bk) * INNER + col0 + bn);
        __syncthreads();
        As[lk + 0][lm] = av.x; As[lk + 1][lm] = av.y;
        As[lk + 2][lm] = av.z; As[lk + 3][lm] = av.w;
        *(float4*)&Bs[bk][bn] = bv;
        __syncthreads();
#pragma unroll
        for (int k = 0; k < 16; k++) {
            float a[4], b4[4];
            *(float4*)a  = *(const float4*)&As[k][ty * 4];
            *(float4*)b4 = *(const float4*)&Bs[k][tx * 4];
#pragma unroll
            for (int r = 0; r < 4; r++)
#pragma unroll
                for (int c = 0; c < 4; c++)
                    acc[r][c] = fmaf(a[r], b4[c], acc[r][c]);
        }
    }

    if (is_fx) {
        float4 bias = *(const float4*)(bfx + col0 + tx * 4);
#pragma unroll
        for (int r = 0; r < 4; r++) {
            const size_t row = (size_t)mtile * 64 + ty * 4 + r;
            ushort4 u;
            u.x = f2bf(acc[r][0] + bias.x);
            u.y = f2bf(acc[r][1] + bias.y);
            u.z = f2bf(acc[r][2] + bias.z);
            u.w = f2bf(acc[r][3] + bias.w);
            *(ushort4*)(fx_out + row * INNER + col0 + tx * 4) = u;
        }
    } else {
        float4 bias = *(const float4*)(bx + col0 + tx * 4);
#pragma unroll
        for (int r = 0; r < 4; r++) {
            xm[ty * 4 + r][tx * 4 + 0] = acc[r][0] + bias.x;
            xm[ty * 4 + r][tx * 4 + 1] = acc[r][1] + bias.y;
            xm[ty * 4 + r][tx * 4 + 2] = acc[r][2] + bias.z;
            xm[ty * 4 + r][tx * 4 + 3] = acc[r][3] + bias.w;
        }
        __syncthreads();
        // softmax phase: thread -> (point p, quarter gq of g-range)
        const int p  = t >> 2;
        const int gq = t & 3;
        float tv = temp[h];
        tv = fminf(fmaxf(tv, 0.1f), 5.0f);
        const float itemp = 1.0f / tv;

        float lg[16];
#pragma unroll
        for (int j = 0; j < 16; j++) lg[j] = bsl[gq * 16 + j];
        for (int k = 0; k < 64; k++) {
            const float xv = xm[p][k];
            const float4* wrow = (const float4*)&WslS[k][gq * 16];
#pragma unroll
            for (int j4 = 0; j4 < 4; j4++) {
                float4 wv = wrow[j4];
                lg[j4 * 4 + 0] = fmaf(xv, wv.x, lg[j4 * 4 + 0]);
                lg[j4 * 4 + 1] = fmaf(xv, wv.y, lg[j4 * 4 + 1]);
                lg[j4 * 4 + 2] = fmaf(xv, wv.z, lg[j4 * 4 + 2]);
                lg[j4 * 4 + 3] = fmaf(xv, wv.w, lg[j4 * 4 + 3]);
            }
        }
        float mx = -1e30f;
#pragma unroll
        for (int j = 0; j < 16; j++) { lg[j] *= itemp; mx = fmaxf(mx, lg[j]); }
        mx = fmaxf(mx, __shfl_xor(mx, 1));
        mx = fmaxf(mx, __shfl_xor(mx, 2));
        float s = 0.f;
#pragma unroll
        for (int j = 0; j < 16; j++) { lg[j] = __expf(lg[j] - mx); s += lg[j]; }
        s += __shfl_xor(s, 1);
        s += __shfl_xor(s, 2);
        const float invs = 1.0f / s;

        const size_t row = (size_t)mtile * 64 + p;
        unsigned short* wp = w_out + row * INNER + col0 + gq * 16;
#pragma unroll
        for (int j4 = 0; j4 < 4; j4++) {
            ushort4 u;
            u.x = f2bf(lg[j4 * 4 + 0] * invs);
            u.y = f2bf(lg[j4 * 4 + 1] * invs);
            u.z = f2bf(lg[j4 * 4 + 2] * invs);
            u.w = f2bf(lg[j4 * 4 + 3] * invs);
            *(ushort4*)(wp + j4 * 4) = u;
        }
    }
}

// ---------------------------------------------------------------------------
// K2: pooling split-K. grid (chunk=64, h=8, b=4). Each block reduces 512
// points into a 64x64 register-tiled accumulator, atomicAdd to global.
// thread -> (g = t>>2, d-range = (t&3)*16..+16)
// ---------------------------------------------------------------------------
__global__ __launch_bounds__(256) void k_pool(
    const unsigned short* __restrict__ fx,
    const unsigned short* __restrict__ w,
    float* __restrict__ token_num, float* __restrict__ norm)
{
    const int chunk = blockIdx.x;
    const int h = blockIdx.y;
    const int b = blockIdx.z;
    const int t = threadIdx.x;
    const int g = t >> 2;
    const int dq = t & 3;

    __shared__ float wS[16][64];
    __shared__ float fS[16][64];

    float acc[16] = {};
    float nacc = 0.f;
    const size_t rowbase = ((size_t)b * NPTS + (size_t)chunk * 512) * INNER + h * 64;

    for (int p0 = 0; p0 < 512; p0 += 16) {
        __syncthreads();
#pragma unroll
        for (int i = 0; i < 2; i++) {
            int idx = t + i * 256;          // 0..511
            int p = idx >> 5, u = idx & 31; // point, uint-column
            const size_t off = rowbase + (size_t)(p0 + p) * INNER + u * 2;
            uint32 wv = *(const uint32*)(w + off);
            uint32 fv = *(const uint32*)(fx + off);
            wS[p][u * 2]     = bflo(wv);
            wS[p][u * 2 + 1] = bfhi(wv);
            fS[p][u * 2]     = bflo(fv);
            fS[p][u * 2 + 1] = bfhi(fv);
        }
        __syncthreads();
#pragma unroll
        for (int p = 0; p < 16; p++) {
            const float wv = wS[p][g];
            if (dq == 0) nacc += wv;
#pragma unroll
            for (int i4 = 0; i4 < 4; i4++) {
                float4 f = *(const float4*)&fS[p][dq * 16 + i4 * 4];
                acc[i4 * 4 + 0] = fmaf(wv, f.x, acc[i4 * 4 + 0]);
                acc[i4 * 4 + 1] = fmaf(wv, f.y, acc[i4 * 4 + 1]);
                acc[i4 * 4 + 2] = fmaf(wv, f.z, acc[i4 * 4 + 2]);
                acc[i4 * 4 + 3] = fmaf(wv, f.w, acc[i4 * 4 + 3]);
            }
        }
    }
    float* tn = token_num + ((((size_t)b * HEADS + h) * 64 + g) * 64) + dq * 16;
#pragma unroll
    for (int i = 0; i < 16; i++) atomicAdd(tn + i, acc[i]);
    if (dq == 0) atomicAdd(norm + ((size_t)b * HEADS + h) * 64 + g, nacc);
}

// ---------------------------------------------------------------------------
// K3: tiny attention over 64 slice tokens per (b,h). 32 blocks, 256 threads.
// thread -> (row gg = t>>2, quarter qq = t&3 of 64 cols)
// ---------------------------------------------------------------------------
__global__ __launch_bounds__(256) void k_attn(
    const float* __restrict__ token_num, const float* __restrict__ norm,
    const float* __restrict__ Wq, const float* __restrict__ Wk,
    const float* __restrict__ Wv, float* __restrict__ out_slice)
{
    const int bh = blockIdx.x;
    const int t = threadIdx.x;
    const int gg = t >> 2, qq = t & 3;

    __shared__ float tok[64][68];
    __shared__ float qS[64][68];
    __shared__ float kS[64][68];
    __shared__ float vS[64][68];
    __shared__ float pS[64][68];
    __shared__ float Wqs[64][64], Wks[64][64], Wvs[64][64];

    for (int i = t; i < 4096; i += 256) {
        int g = i >> 6, dd = i & 63;
        Wqs[g][dd] = Wq[i];
        Wks[g][dd] = Wk[i];
        Wvs[g][dd] = Wv[i];
        tok[g][dd] = token_num[(size_t)bh * 4096 + i] / (norm[bh * 64 + g] + 1e-5f);
    }
    __syncthreads();

    float aq[16] = {}, ak[16] = {}, av[16] = {};
    for (int k = 0; k < 64; k++) {
        const float tv = tok[gg][k];
        const float4* wq4 = (const float4*)&Wqs[k][qq * 16];
        const float4* wk4 = (const float4*)&Wks[k][qq * 16];
        const float4* wv4 = (const float4*)&Wvs[k][qq * 16];
#pragma unroll
        for (int j4 = 0; j4 < 4; j4++) {
            float4 a = wq4[j4], bq = wk4[j4], c = wv4[j4];
            aq[j4*4+0] = fmaf(tv, a.x,  aq[j4*4+0]);
            aq[j4*4+1] = fmaf(tv, a.y,  aq[j4*4+1]);
            aq[j4*4+2] = fmaf(tv, a.z,  aq[j4*4+2]);
            aq[j4*4+3] = fmaf(tv, a.w,  aq[j4*4+3]);
            ak[j4*4+0] = fmaf(tv, bq.x, ak[j4*4+0]);
            ak[j4*4+1] = fmaf(tv, bq.y, ak[j4*4+1]);
            ak[j4*4+2] = fmaf(tv, bq.z, ak[j4*4+2]);
            ak[j4*4+3] = fmaf(tv, bq.w, ak[j4*4+3]);
            av[j4*4+0] = fmaf(tv, c.x,  av[j4*4+0]);
            av[j4*4+1] = fmaf(tv, c.y,  av[j4*4+1]);
            av[j4*4+2] = fmaf(tv, c.z,  av[j4*4+2]);
            av[j4*4+3] = fmaf(tv, c.w,  av[j4*4+3]);
        }
    }
#pragma unroll
    for (int j = 0; j < 16; j++) {
        qS[gg][qq * 16 + j] = aq[j];
        kS[gg][qq * 16 + j] = ak[j];
        vS[gg][qq * 16 + j] = av[j];
    }
    __syncthreads();

    // scores S[gg][qq*16+j] = sum_d q[gg][d] * k[qq*16+j][d]
    float sc[16] = {};
    for (int d4 = 0; d4 < 16; d4++) {
        float4 q4 = *(const float4*)&qS[gg][d4 * 4];
#pragma unroll
        for (int j = 0; j < 16; j++) {
            float4 k4 = *(const float4*)&kS[qq * 16 + j][d4 * 4];
            sc[j] = fmaf(q4.x, k4.x, sc[j]);
            sc[j] = fmaf(q4.y, k4.y, sc[j]);
            sc[j] = fmaf(q4.z, k4.z, sc[j]);
            sc[j] = fmaf(q4.w, k4.w, sc[j]);
        }
    }
    const float SCALE = 0.125f;  // 64^-0.5
    float mx = -1e30f;
#pragma unroll
    for (int j = 0; j < 16; j++) { sc[j] *= SCALE; mx = fmaxf(mx, sc[j]); }
    mx = fmaxf(mx, __shfl_xor(mx, 1));
    mx = fmaxf(mx, __shfl_xor(mx, 2));
    float s = 0.f;
#pragma unroll
    for (int j = 0; j < 16; j++) { sc[j] = __expf(sc[j] - mx); s += sc[j]; }
    s += __shfl_xor(s, 1);
    s += __shfl_xor(s, 2);
    const float invs = 1.0f / s;
#pragma unroll
    for (int j = 0; j < 16; j++) pS[gg][qq * 16 + j] = sc[j] * invs;
    __syncthreads();

    float oo[16] = {};
    for (int j = 0; j < 64; j++) {
        const float pv = pS[gg][j];
        const float4* v4p = (const float4*)&vS[j][qq * 16];
#pragma unroll
        for (int d4 = 0; d4 < 4; d4++) {
            float4 v4 = v4p[d4];
            oo[d4*4+0] = fmaf(pv, v4.x, oo[d4*4+0]);
            oo[d4*4+1] = fmaf(pv, v4.y, oo[d4*4+1]);
            oo[d4*4+2] = fmaf(pv, v4.z, oo[d4*4+2]);
            oo[d4*4+3] = fmaf(pv, v4.w, oo[d4*4+3]);
        }
    }
    float* op = out_slice + (size_t)bh * 4096 + gg * 64 + qq * 16;
#pragma unroll
    for (int d4 = 0; d4 < 4; d4++) {
        float4 o; o.x = oo[d4*4+0]; o.y = oo[d4*4+1]; o.z = oo[d4*4+2]; o.w = oo[d4*4+3];
        *(float4*)(op + d4 * 4) = o;
    }
}

// ---------------------------------------------------------------------------
// K4: M[b][hg][c] = sum_d out_slice[b][h][g][d] * W_out[h*64+d][c]
// grid = b*512 blocks, 256 threads (thread = output column c)
// ---------------------------------------------------------------------------
__global__ __launch_bounds__(256) void k_m(
    const float* __restrict__ out_slice, const float* __restrict__ W_out,
    float* __restrict__ M)
{
    const int idx = blockIdx.x;          // b*512 + h*64 + g
    const int h = (idx >> 6) & 7;
    const int t = threadIdx.x;
    __shared__ float os[64];
    if (t < 64) os[t] = out_slice[(size_t)idx * 64 + t];
    __syncthreads();
    float acc = 0.f;
#pragma unroll 8
    for (int d = 0; d < 64; d++)
        acc = fmaf(os[d], W_out[(size_t)(h * 64 + d) * DIM + t], acc);
    M[(size_t)idx * DIM + t] = acc;
}

// ---------------------------------------------------------------------------
// K5: out[m][c] = sum_k w[m][k] * M[b][k][c] + b_out[c]   (K=512, per-b M)
// ---------------------------------------------------------------------------
__global__ __launch_bounds__(256) void k_out(
    const unsigned short* __restrict__ w, const float* __restrict__ M,
    const float* __restrict__ b_out, float* __restrict__ out)
{
    const int mtile = blockIdx.x;     // Mtotal/64
    const int ntile = blockIdx.y;     // 4
    const int b = mtile >> 9;         // 512 row-tiles per batch
    const int col0 = ntile * 64;

    __shared__ float As[16][68];
    __shared__ float Bs[16][64];

    const int t = threadIdx.x;
    const int ty = t >> 4, tx = t & 15;
    const int lm = t >> 2, lk = (t & 3) * 4;
    const int bk = t >> 4, bn = (t & 15) * 4;

    float acc[4][4] = {};
    const unsigned short* Arow = w + (size_t)mtile * 64 * INNER;
    const float* Bmat = M + (size_t)b * INNER * DIM;

    for (int kb = 0; kb < INNER; kb += 16) {
        uint2 a2 = *(const uint2*)(Arow + (size_t)lm * INNER + kb + lk);
        float4 bv = *(const float4*)(Bmat + (size_t)(kb + bk) * DIM + col0 + bn);
        __syncthreads();
        As[lk + 0][lm] = bflo(a2.x);
        As[lk + 1][lm] = bfhi(a2.x);
        As[lk + 2][lm] = bflo(a2.y);
        As[lk + 3][lm] = bfhi(a2.y);
        *(float4*)&Bs[bk][bn] = bv;
        __syncthreads();
#pragma unroll
        for (int k = 0; k < 16; k++) {
            float a[4], b4[4];
            *(float4*)a  = *(const float4*)&As[k][ty * 4];
            *(float4*)b4 = *(const float4*)&Bs[k][tx * 4];
#pragma unroll
            for (int r = 0; r < 4; r++)
#pragma unroll
                for (int c = 0; c < 4; c++)
                    acc[r][c] = fmaf(a[r], b4[c], acc[r][c]);
        }
    }

    float4 bias = *(const float4*)(b_out + col0 + tx * 4);
#pragma unroll
    for (int r = 0; r < 4; r++) {
        float4 o;
        o.x = acc[r][0] + bias.x;
        o.y = acc[r][1] + bias.y;
        o.z = acc[r][2] + bias.z;
        o.w = acc[r][3] + bias.w;
        *(float4*)(out + ((size_t)mtile * 64 + ty * 4 + r) * DIM + col0 + tx * 4) = o;
    }
}

// ---------------------------------------------------------------------------
extern "C" void kernel_launch(void* const* d_in, const int* in_sizes, int n_in,
                              void* d_out, int out_size, void* d_ws, size_t ws_size,
                              hipStream_t stream) {
    const float* x    = (const float*)d_in[0];
    const float* Wfx  = (const float*)d_in[1];
    const float* bfx  = (const float*)d_in[2];
    const float* Wx   = (const float*)d_in[3];
    const float* bx   = (const float*)d_in[4];
    const float* Wsl  = (const float*)d_in[5];
    const float* bsl  = (const float*)d_in[6];
    const float* temp = (const float*)d_in[7];
    const float* Wq   = (const float*)d_in[8];
    const float* Wk   = (const float*)d_in[9];
    const float* Wv   = (const float*)d_in[10];
    const float* Wout = (const float*)d_in[11];
    const float* bout = (const float*)d_in[12];
    float* out = (float*)d_out;

    const int Mtotal = in_sizes[0] / DIM;   // b*n = 131072
    const int B = Mtotal / NPTS;            // 4

    char* p = (char*)d_ws;
    unsigned short* fx_ws = (unsigned short*)p; p += (size_t)Mtotal * INNER * 2;
    unsigned short* w_ws  = (unsigned short*)p; p += (size_t)Mtotal * INNER * 2;
    float* token_num = (float*)p; p += (size_t)B * HEADS * 64 * 64 * 4;
    float* norm_ws   = (float*)p; p += (size_t)B * HEADS * 64 * 4;
    float* os_ws     = (float*)p; p += (size_t)B * HEADS * 64 * 64 * 4;
    float* M_ws      = (float*)p; p += (size_t)B * INNER * DIM * 4;

    // zero the split-K accumulators (token_num + norm are contiguous)
    hipMemsetAsync(token_num, 0,
                   (size_t)B * HEADS * 64 * 64 * 4 + (size_t)B * HEADS * 64 * 4,
                   stream);

    k_proj<<<dim3(Mtotal / 64, 16), 256, 0, stream>>>(
        x, Wfx, bfx, Wx, bx, Wsl, bsl, temp, fx_ws, w_ws);
    k_pool<<<dim3(64, HEADS, B), 256, 0, stream>>>(
        fx_ws, w_ws, token_num, norm_ws);
    k_attn<<<B * HEADS, 256, 0, stream>>>(
        token_num, norm_ws, Wq, Wk, Wv, os_ws);
    k_m<<<B * INNER, 256, 0, stream>>>(os_ws, Wout, M_ws);
    k_out<<<dim3(Mtotal / 64, 4), 256, 0, stream>>>(
        w_ws, M_ws, bout, out);
}

// Round 3
// 878.304 us; speedup vs baseline: 2.6438x; 2.6438x over previous
//
#include <hip/hip_runtime.h>
#include <hip/hip_bf16.h>
#include <stdint.h>

#define DIM 256
#define HEADS 8
#define INNER 512
#define NPTS 32768

typedef unsigned int uint32;
typedef short bf16x8 __attribute__((ext_vector_type(8)));
typedef float f32x4 __attribute__((ext_vector_type(4)));

static __device__ __forceinline__ unsigned short f2bf(float f) {
    unsigned int u = __float_as_uint(f);
    u += 0x7fffu + ((u >> 16) & 1u);   // round-to-nearest-even
    return (unsigned short)(u >> 16);
}
static __device__ __forceinline__ float bf2f(unsigned short v) {
    return __uint_as_float(((unsigned int)v) << 16);
}
static __device__ __forceinline__ uint32 pkbf(float a, float b) {
    __hip_bfloat162 h = __float22bfloat162_rn(make_float2(a, b));
    return *(reinterpret_cast<uint32*>(&h));
}
static __device__ __forceinline__ void gll16(const void* g, const void* l) {
    __builtin_amdgcn_global_load_lds(
        (const __attribute__((address_space(1))) uint32*)g,
        (__attribute__((address_space(3))) uint32*)l, 16, 0, 0);
}

// ---------------------------------------------------------------------------
// K0: prep — Wfx|Wx -> combined transposed bf16 [1024][256]; Wsl -> [g][d]
// ---------------------------------------------------------------------------
__global__ __launch_bounds__(256) void k_prep(
    const float* __restrict__ Wfx, const float* __restrict__ Wx,
    const float* __restrict__ Wsl,
    unsigned short* __restrict__ Wbt, unsigned short* __restrict__ WslT)
{
    const int blk = blockIdx.x, t = threadIdx.x;
    if (blk < 4) {
        const int n = blk * 256 + t;
        for (int k8 = 0; k8 < 256; k8 += 8) {
            unsigned short v[8];
#pragma unroll
            for (int j = 0; j < 8; j++) {
                float f = (n < 512) ? Wfx[(size_t)(k8 + j) * 512 + n]
                                    : Wx[(size_t)(k8 + j) * 512 + (n - 512)];
                v[j] = f2bf(f);
            }
            ushort4 u0 = {v[0], v[1], v[2], v[3]};
            ushort4 u1 = {v[4], v[5], v[6], v[7]};
            *(ushort4*)(Wbt + (size_t)n * 256 + k8) = u0;
            *(ushort4*)(Wbt + (size_t)n * 256 + k8 + 4) = u1;
        }
    } else {
        // WslT[g][d] = Wsl[d][g]
        const int g = t >> 2, d0 = (t & 3) * 16;
        unsigned short v[16];
#pragma unroll
        for (int i = 0; i < 16; i++) v[i] = f2bf(Wsl[(size_t)(d0 + i) * 64 + g]);
#pragma unroll
        for (int q = 0; q < 4; q++) {
            ushort4 u = {v[q * 4], v[q * 4 + 1], v[q * 4 + 2], v[q * 4 + 3]};
            *(ushort4*)(WslT + (size_t)g * 64 + d0 + q * 4) = u;
        }
    }
}

// ---------------------------------------------------------------------------
// K1: fused projection MFMA GEMM + slice softmax.
// grid (8 ntiles fast, Mtotal/128). ntile 0..3 -> fx cols, 4..7 -> x_mid cols.
// A-tile staged from fp32 x via register cvt (no xb buffer).
// Outputs: fxT[(b h d)][n], wT[(b h g)][n] (transposed), norm atomics.
// ---------------------------------------------------------------------------
__global__ __launch_bounds__(256, 2) void k_proj(
    const float* __restrict__ x,               // [M][256] fp32
    const unsigned short* __restrict__ Wbt,    // [1024][256] bf16
    const float* __restrict__ bfx, const float* __restrict__ bx,
    const unsigned short* __restrict__ WslTg,  // [64 g][64 d] bf16
    const float* __restrict__ bsl, const float* __restrict__ temp,
    unsigned short* __restrict__ fxT,
    unsigned short* __restrict__ wT,
    float* __restrict__ norm)
{
    __shared__ unsigned short R1s[128 * 136];  // A[128][64]+B[128][64] | fxS/xm[128][136] | wsmT
    __shared__ unsigned short WslS[64 * 64];

    const int ntile = blockIdx.x;
    const int mtile = blockIdx.y;
    const int m0 = mtile * 128;
    const int col0 = ntile * 128;
    const int t = threadIdx.x;
    const int w = t >> 6, lane = t & 63;
    const int wm = w >> 1, wn = w & 1;
    const int l15 = lane & 15, quad = lane >> 4;
    const int b = m0 >> 15;
    const int n_in_b = m0 & (NPTS - 1);

    unsigned short* A = R1s;              // [128][64]
    unsigned short* Bs = R1s + 128 * 64;  // [128][64]

    if (ntile >= 4) {
        *(uint4*)&WslS[t * 8] = *(const uint4*)&WslTg[t * 8];
        *(uint4*)&WslS[2048 + t * 8] = *(const uint4*)&WslTg[2048 + t * 8];
    }

    f32x4 acc[4][4];
#pragma unroll
    for (int r = 0; r < 4; r++)
#pragma unroll
        for (int c = 0; c < 4; c++) acc[r][c] = (f32x4){0.f, 0.f, 0.f, 0.f};

    for (int kb = 0; kb < 256; kb += 64) {
        // prefetch A (fp32) into registers — before barrier, overlaps prior MFMA
        float4 a0[4], a1[4];
#pragma unroll
        for (int rr = 0; rr < 4; rr++) {
            int flat = rr * 256 + t;
            int row = flat >> 3, colg = (flat & 7) * 8;
            const float* src = x + (size_t)(m0 + row) * 256 + kb + colg;
            a0[rr] = *(const float4*)src;
            a1[rr] = *(const float4*)(src + 4);
        }
        __syncthreads();
#pragma unroll
        for (int rr = 0; rr < 4; rr++) {
            int flat = rr * 256 + t;
            int row = flat >> 3, colg = (flat & 7) * 8;
            gll16(Wbt + (size_t)(col0 + row) * 256 + kb + colg, (char*)Bs + flat * 16);
        }
#pragma unroll
        for (int rr = 0; rr < 4; rr++) {
            int flat = rr * 256 + t;
            int row = flat >> 3, colg = (flat & 7) * 8;
            uint4 v;
            v.x = pkbf(a0[rr].x, a0[rr].y);
            v.y = pkbf(a0[rr].z, a0[rr].w);
            v.z = pkbf(a1[rr].x, a1[rr].y);
            v.w = pkbf(a1[rr].z, a1[rr].w);
            *(uint4*)&A[row * 64 + colg] = v;
        }
        __syncthreads();
#pragma unroll
        for (int ks = 0; ks < 2; ks++) {
            bf16x8 af[4], bfv[4];
#pragma unroll
            for (int r = 0; r < 4; r++)
                af[r] = *(const bf16x8*)&A[(wm * 64 + r * 16 + l15) * 64 + ks * 32 + quad * 8];
#pragma unroll
            for (int c = 0; c < 4; c++)
                bfv[c] = *(const bf16x8*)&Bs[(wn * 64 + c * 16 + l15) * 64 + ks * 32 + quad * 8];
#pragma unroll
            for (int r = 0; r < 4; r++)
#pragma unroll
                for (int c = 0; c < 4; c++)
                    acc[r][c] = __builtin_amdgcn_mfma_f32_16x16x32_bf16(af[r], bfv[c], acc[r][c], 0, 0, 0);
        }
    }

    if (ntile < 4) {
        // ---------- fx epilogue: LDS transpose -> fxT[(b h d)][n] ----------
        float biasc[4];
#pragma unroll
        for (int c = 0; c < 4; c++) biasc[c] = bfx[col0 + wn * 64 + c * 16 + l15];
        __syncthreads();
        unsigned short* fxS = R1s;  // [128 col][136 m]
#pragma unroll
        for (int r = 0; r < 4; r++)
#pragma unroll
            for (int c = 0; c < 4; c++) {
                ushort4 u;
                u.x = f2bf(acc[r][c][0] + biasc[c]);
                u.y = f2bf(acc[r][c][1] + biasc[c]);
                u.z = f2bf(acc[r][c][2] + biasc[c]);
                u.w = f2bf(acc[r][c][3] + biasc[c]);
                *(ushort4*)&fxS[(wn * 64 + c * 16 + l15) * 136 + wm * 64 + r * 16 + quad * 4] = u;
            }
        __syncthreads();
        const int colL = t >> 1, half = t & 1;
        const int h = (col0 + colL) >> 6, d = (col0 + colL) & 63;
        unsigned short* dst = fxT + (((size_t)(b * 8 + h) * 64 + d) << 15) + n_in_b + half * 64;
        const unsigned short* src = &fxS[colL * 136 + half * 64];
#pragma unroll
        for (int i = 0; i < 8; i++)          // 8 x uint4 = 64 shorts
            *(uint4*)(dst + i * 8) = *(const uint4*)(src + i * 8);
    } else {
        // ---------- x_mid epilogue: logits MFMA + softmax -> wT ----------
        const int hloc = (ntile - 4) * 2;
        const int head = hloc + wn;       // wave wn owns head hloc+wn
        float biasc[4];
#pragma unroll
        for (int c = 0; c < 4; c++) biasc[c] = bx[(col0 - 512) + wn * 64 + c * 16 + l15];
        __syncthreads();
        unsigned short* xm = R1s;  // [128 m][136 d]
#pragma unroll
        for (int r = 0; r < 4; r++)
#pragma unroll
            for (int c = 0; c < 4; c++)
#pragma unroll
                for (int j = 0; j < 4; j++)
                    xm[(wm * 64 + r * 16 + quad * 4 + j) * 136 + wn * 64 + c * 16 + l15] =
                        f2bf(acc[r][c][j] + biasc[c]);
        __syncthreads();

        float tv = temp[head];
        tv = fminf(fmaxf(tv, 0.1f), 5.0f);
        const float itemp = 1.0f / tv;

        f32x4 lacc[4][4];
#pragma unroll
        for (int c = 0; c < 4; c++) {
            float bv = bsl[c * 16 + l15];
#pragma unroll
            for (int r = 0; r < 4; r++) lacc[r][c] = (f32x4){bv, bv, bv, bv};
        }
#pragma unroll
        for (int ks = 0; ks < 2; ks++) {
            bf16x8 af[4], bfv[4];
#pragma unroll
            for (int r = 0; r < 4; r++)
                af[r] = *(const bf16x8*)&xm[(wm * 64 + r * 16 + l15) * 136 + wn * 64 + ks * 32 + quad * 8];
#pragma unroll
            for (int c = 0; c < 4; c++)
                bfv[c] = *(const bf16x8*)&WslS[(c * 16 + l15) * 64 + ks * 32 + quad * 8];
#pragma unroll
            for (int r = 0; r < 4; r++)
#pragma unroll
                for (int c = 0; c < 4; c++)
                    lacc[r][c] = __builtin_amdgcn_mfma_f32_16x16x32_bf16(af[r], bfv[c], lacc[r][c], 0, 0, 0);
        }
        __syncthreads();  // done reading xm; reuse region as wsmT

        unsigned short* wsmT = R1s;  // [2 wn][64 g][136 m]
        float ns[4] = {0.f, 0.f, 0.f, 0.f};
#pragma unroll
        for (int r = 0; r < 4; r++) {
            float wv[4][4];
#pragma unroll
            for (int j = 0; j < 4; j++) {
                float v0 = lacc[r][0][j] * itemp;
                float v1 = lacc[r][1][j] * itemp;
                float v2 = lacc[r][2][j] * itemp;
                float v3 = lacc[r][3][j] * itemp;
                float mx = fmaxf(fmaxf(v0, v1), fmaxf(v2, v3));
                mx = fmaxf(mx, __shfl_xor(mx, 1));
                mx = fmaxf(mx, __shfl_xor(mx, 2));
                mx = fmaxf(mx, __shfl_xor(mx, 4));
                mx = fmaxf(mx, __shfl_xor(mx, 8));
                float e0 = __expf(v0 - mx), e1 = __expf(v1 - mx);
                float e2 = __expf(v2 - mx), e3 = __expf(v3 - mx);
                float s = e0 + e1 + e2 + e3;
                s += __shfl_xor(s, 1);
                s += __shfl_xor(s, 2);
                s += __shfl_xor(s, 4);
                s += __shfl_xor(s, 8);
                float inv = 1.0f / s;
                wv[0][j] = e0 * inv; wv[1][j] = e1 * inv;
                wv[2][j] = e2 * inv; wv[3][j] = e3 * inv;
                ns[0] += wv[0][j]; ns[1] += wv[1][j];
                ns[2] += wv[2][j]; ns[3] += wv[3][j];
            }
#pragma unroll
            for (int c = 0; c < 4; c++) {
                ushort4 u;
                u.x = f2bf(wv[c][0]); u.y = f2bf(wv[c][1]);
                u.z = f2bf(wv[c][2]); u.w = f2bf(wv[c][3]);
                *(ushort4*)&wsmT[(wn * 64 + c * 16 + l15) * 136 + wm * 64 + r * 16 + quad * 4] = u;
            }
        }
#pragma unroll
        for (int c = 0; c < 4; c++) {
            ns[c] += __shfl_xor(ns[c], 16);
            ns[c] += __shfl_xor(ns[c], 32);
        }
        if (quad == 0) {
#pragma unroll
            for (int c = 0; c < 4; c++)
                atomicAdd(norm + ((size_t)b * 8 + head) * 64 + c * 16 + l15, ns[c]);
        }
        __syncthreads();
        const int wnn = t >> 7, g = (t >> 1) & 63, half = t & 1;
        const int headg = hloc + wnn;
        unsigned short* dst = wT + (((size_t)(b * 8 + headg) * 64 + g) << 15) + n_in_b + half * 64;
        const unsigned short* src = &wsmT[(wnn * 64 + g) * 136 + half * 64];
#pragma unroll
        for (int i = 0; i < 8; i++)          // 8 x uint4 = 64 shorts
            *(uint4*)(dst + i * 8) = *(const uint4*)(src + i * 8);
    }
}

// ---------------------------------------------------------------------------
// K2: pooling split-K MFMA. token[g][d] = sum_n wT[g][n] * fxT[d][n].
// ---------------------------------------------------------------------------
#define POOL_SPLIT 16
__global__ __launch_bounds__(256) void k_pool(
    const unsigned short* __restrict__ wT,
    const unsigned short* __restrict__ fxT,
    float* __restrict__ token_num)
{
    __shared__ unsigned short Ap[64 * 64];
    __shared__ unsigned short Bp[64 * 64];
    const int chunk = blockIdx.x, h = blockIdx.y, b = blockIdx.z;
    const int t = threadIdx.x;
    const int w = t >> 6, lane = t & 63, l15 = lane & 15, quad = lane >> 4;
    const size_t base = ((size_t)(b * 8 + h) * 64) << 15;
    const int CH = NPTS / POOL_SPLIT;
    const int n00 = chunk * CH;

    f32x4 acc[4];
#pragma unroll
    for (int c = 0; c < 4; c++) acc[c] = (f32x4){0.f, 0.f, 0.f, 0.f};

    for (int ks0 = 0; ks0 < CH; ks0 += 64) {
        __syncthreads();
#pragma unroll
        for (int rr = 0; rr < 2; rr++) {
            int flat = rr * 256 + t;
            int row = flat >> 3, col = (flat & 7) * 8;
            gll16(wT + base + ((size_t)row << 15) + n00 + ks0 + col, (char*)Ap + flat * 16);
            gll16(fxT + base + ((size_t)row << 15) + n00 + ks0 + col, (char*)Bp + flat * 16);
        }
        __syncthreads();
#pragma unroll
        for (int ks = 0; ks < 2; ks++) {
            bf16x8 af = *(const bf16x8*)&Ap[(w * 16 + l15) * 64 + ks * 32 + quad * 8];
            bf16x8 bfv[4];
#pragma unroll
            for (int c = 0; c < 4; c++)
                bfv[c] = *(const bf16x8*)&Bp[(c * 16 + l15) * 64 + ks * 32 + quad * 8];
#pragma unroll
            for (int c = 0; c < 4; c++)
                acc[c] = __builtin_amdgcn_mfma_f32_16x16x32_bf16(af, bfv[c], acc[c], 0, 0, 0);
        }
    }
    float* tn = token_num + ((size_t)(b * 8 + h) * 64) * 64;
#pragma unroll
    for (int c = 0; c < 4; c++)
#pragma unroll
        for (int j = 0; j < 4; j++)
            atomicAdd(tn + (size_t)(w * 16 + quad * 4 + j) * 64 + c * 16 + l15, acc[c][j]);
}

// ---------------------------------------------------------------------------
// K3: tiny attention over 64 slice tokens per (b,h). (unchanged; passed R1)
// ---------------------------------------------------------------------------
__global__ __launch_bounds__(256) void k_attn(
    const float* __restrict__ token_num, const float* __restrict__ norm,
    const float* __restrict__ Wq, const float* __restrict__ Wk,
    const float* __restrict__ Wv, float* __restrict__ out_slice)
{
    const int bh = blockIdx.x;
    const int t = threadIdx.x;
    const int gg = t >> 2, qq = t & 3;

    __shared__ float tok[64][68];
    __shared__ float qS[64][68];
    __shared__ float kS[64][68];
    __shared__ float vS[64][68];
    __shared__ float pS[64][68];
    __shared__ float Wqs[64][64], Wks[64][64], Wvs[64][64];

    for (int i = t; i < 4096; i += 256) {
        int g = i >> 6, dd = i & 63;
        Wqs[g][dd] = Wq[i];
        Wks[g][dd] = Wk[i];
        Wvs[g][dd] = Wv[i];
        tok[g][dd] = token_num[(size_t)bh * 4096 + i] / (norm[bh * 64 + g] + 1e-5f);
    }
    __syncthreads();

    float aq[16] = {}, ak[16] = {}, av[16] = {};
    for (int k = 0; k < 64; k++) {
        const float tv = tok[gg][k];
        const float4* wq4 = (const float4*)&Wqs[k][qq * 16];
        const float4* wk4 = (const float4*)&Wks[k][qq * 16];
        const float4* wv4 = (const float4*)&Wvs[k][qq * 16];
#pragma unroll
        for (int j4 = 0; j4 < 4; j4++) {
            float4 a = wq4[j4], bq = wk4[j4], c = wv4[j4];
            aq[j4*4+0] = fmaf(tv, a.x,  aq[j4*4+0]);
            aq[j4*4+1] = fmaf(tv, a.y,  aq[j4*4+1]);
            aq[j4*4+2] = fmaf(tv, a.z,  aq[j4*4+2]);
            aq[j4*4+3] = fmaf(tv, a.w,  aq[j4*4+3]);
            ak[j4*4+0] = fmaf(tv, bq.x, ak[j4*4+0]);
            ak[j4*4+1] = fmaf(tv, bq.y, ak[j4*4+1]);
            ak[j4*4+2] = fmaf(tv, bq.z, ak[j4*4+2]);
            ak[j4*4+3] = fmaf(tv, bq.w, ak[j4*4+3]);
            av[j4*4+0] = fmaf(tv, c.x,  av[j4*4+0]);
            av[j4*4+1] = fmaf(tv, c.y,  av[j4*4+1]);
            av[j4*4+2] = fmaf(tv, c.z,  av[j4*4+2]);
            av[j4*4+3] = fmaf(tv, c.w,  av[j4*4+3]);
        }
    }
#pragma unroll
    for (int j = 0; j < 16; j++) {
        qS[gg][qq * 16 + j] = aq[j];
        kS[gg][qq * 16 + j] = ak[j];
        vS[gg][qq * 16 + j] = av[j];
    }
    __syncthreads();

    float sc[16] = {};
    for (int d4 = 0; d4 < 16; d4++) {
        float4 q4 = *(const float4*)&qS[gg][d4 * 4];
#pragma unroll
        for (int j = 0; j < 16; j++) {
            float4 k4 = *(const float4*)&kS[qq * 16 + j][d4 * 4];
            sc[j] = fmaf(q4.x, k4.x, sc[j]);
            sc[j] = fmaf(q4.y, k4.y, sc[j]);
            sc[j] = fmaf(q4.z, k4.z, sc[j]);
            sc[j] = fmaf(q4.w, k4.w, sc[j]);
        }
    }
    const float SCALE = 0.125f;
    float mx = -1e30f;
#pragma unroll
    for (int j = 0; j < 16; j++) { sc[j] *= SCALE; mx = fmaxf(mx, sc[j]); }
    mx = fmaxf(mx, __shfl_xor(mx, 1));
    mx = fmaxf(mx, __shfl_xor(mx, 2));
    float s = 0.f;
#pragma unroll
    for (int j = 0; j < 16; j++) { sc[j] = __expf(sc[j] - mx); s += sc[j]; }
    s += __shfl_xor(s, 1);
    s += __shfl_xor(s, 2);
    const float invs = 1.0f / s;
#pragma unroll
    for (int j = 0; j < 16; j++) pS[gg][qq * 16 + j] = sc[j] * invs;
    __syncthreads();

    float oo[16] = {};
    for (int j = 0; j < 64; j++) {
        const float pv = pS[gg][j];
        const float4* v4p = (const float4*)&vS[j][qq * 16];
#pragma unroll
        for (int d4 = 0; d4 < 4; d4++) {
            float4 v4 = v4p[d4];
            oo[d4*4+0] = fmaf(pv, v4.x, oo[d4*4+0]);
            oo[d4*4+1] = fmaf(pv, v4.y, oo[d4*4+1]);
            oo[d4*4+2] = fmaf(pv, v4.z, oo[d4*4+2]);
            oo[d4*4+3] = fmaf(pv, v4.w, oo[d4*4+3]);
        }
    }
    float* op = out_slice + (size_t)bh * 4096 + gg * 64 + qq * 16;
#pragma unroll
    for (int d4 = 0; d4 < 4; d4++) {
        float4 o; o.x = oo[d4*4+0]; o.y = oo[d4*4+1]; o.z = oo[d4*4+2]; o.w = oo[d4*4+3];
        *(float4*)(op + d4 * 4) = o;
    }
}

// ---------------------------------------------------------------------------
// K4: transpose wT[(b h g)][n] -> wN[b n][h*64+g]
// ---------------------------------------------------------------------------
__global__ __launch_bounds__(256) void k_tr(
    const unsigned short* __restrict__ wT, unsigned short* __restrict__ wN)
{
    __shared__ unsigned short tl[64 * 264];
    const int nc = blockIdx.x, h = blockIdx.y, b = blockIdx.z;
    const int t = threadIdx.x;
    const int n0 = nc * 256;
    const size_t base = ((size_t)(b * 8 + h) * 64) << 15;
    {
        const int g = t >> 2, seg = t & 3;
#pragma unroll
        for (int i = 0; i < 8; i++) {        // 8 x uint4 = 64 shorts
            uint4 v = *(const uint4*)(wT + base + ((size_t)g << 15) + n0 + seg * 64 + i * 8);
            *(uint4*)&tl[g * 264 + seg * 64 + i * 8] = v;
        }
    }
    __syncthreads();
    unsigned short* dst = wN + (size_t)(b * NPTS + n0 + t) * 512 + h * 64;
#pragma unroll
    for (int g4 = 0; g4 < 16; g4++) {
        ushort4 u;
        u.x = tl[(g4 * 4 + 0) * 264 + t];
        u.y = tl[(g4 * 4 + 1) * 264 + t];
        u.z = tl[(g4 * 4 + 2) * 264 + t];
        u.w = tl[(g4 * 4 + 3) * 264 + t];
        *(ushort4*)(dst + g4 * 4) = u;
    }
}

// ---------------------------------------------------------------------------
// K5: Mt[c][hg] = sum_d os[b][h][g][d] * W_out[h*64+d][c], split hi/lo bf16
// ---------------------------------------------------------------------------
__global__ __launch_bounds__(256) void k_m(
    const float* __restrict__ os, const float* __restrict__ W_out,
    unsigned short* __restrict__ Mt_hi, unsigned short* __restrict__ Mt_lo)
{
    const int h = blockIdx.x, b = blockIdx.y;
    const int t = threadIdx.x;   // c
    __shared__ float osl[64][65];
    for (int i = t; i < 4096; i += 256)
        osl[i >> 6][i & 63] = os[(size_t)(b * 8 + h) * 4096 + i];
    __syncthreads();
    float acc[64];
#pragma unroll
    for (int g = 0; g < 64; g++) acc[g] = 0.f;
    for (int d = 0; d < 64; d++) {
        float wv = W_out[(size_t)(h * 64 + d) * 256 + t];
#pragma unroll
        for (int g = 0; g < 64; g++) acc[g] = fmaf(osl[g][d], wv, acc[g]);
    }
    unsigned short* ph = Mt_hi + (size_t)(b * 256 + t) * 512 + h * 64;
    unsigned short* pl = Mt_lo + (size_t)(b * 256 + t) * 512 + h * 64;
#pragma unroll
    for (int g4 = 0; g4 < 16; g4++) {
        ushort4 uh, ul;
        unsigned short hh; float v, lo;
        v = acc[g4*4+0]; hh = f2bf(v); lo = v - bf2f(hh); uh.x = hh; ul.x = f2bf(lo);
        v = acc[g4*4+1]; hh = f2bf(v); lo = v - bf2f(hh); uh.y = hh; ul.y = f2bf(lo);
        v = acc[g4*4+2]; hh = f2bf(v); lo = v - bf2f(hh); uh.z = hh; ul.z = f2bf(lo);
        v = acc[g4*4+3]; hh = f2bf(v); lo = v - bf2f(hh); uh.w = hh; ul.w = f2bf(lo);
        *(ushort4*)(ph + g4 * 4) = uh;
        *(ushort4*)(pl + g4 * 4) = ul;
    }
}

// ---------------------------------------------------------------------------
// K6: out[m][c] = sum_k wN[m][k] * (Mt_hi+Mt_lo)[c][k] + bout[c]   (MFMA)
// ---------------------------------------------------------------------------
__global__ __launch_bounds__(256, 2) void k_out(
    const unsigned short* __restrict__ wN,
    const unsigned short* __restrict__ Mt_hi, const unsigned short* __restrict__ Mt_lo,
    const float* __restrict__ bout, float* __restrict__ out)
{
    __shared__ unsigned short A[128 * 64];
    __shared__ unsigned short Bh[128 * 64];
    __shared__ unsigned short Bl[128 * 64];
    const int ntile = blockIdx.x;   // 0..1
    const int mtile = blockIdx.y;
    const int m0 = mtile * 128, col0 = ntile * 128;
    const int b = m0 >> 15;
    const int t = threadIdx.x;
    const int w = t >> 6, lane = t & 63, l15 = lane & 15, quad = lane >> 4;
    const int wm = w >> 1, wn = w & 1;

    f32x4 acc[4][4];
#pragma unroll
    for (int r = 0; r < 4; r++)
#pragma unroll
        for (int c = 0; c < 4; c++) acc[r][c] = (f32x4){0.f, 0.f, 0.f, 0.f};

    for (int kb = 0; kb < 512; kb += 64) {
        __syncthreads();
#pragma unroll
        for (int rr = 0; rr < 4; rr++) {
            int flat = rr * 256 + t;
            int row = flat >> 3, col = (flat & 7) * 8;
            gll16(wN + (size_t)(m0 + row) * 512 + kb + col, (char*)A + flat * 16);
            gll16(Mt_hi + (size_t)(b * 256 + col0 + row) * 512 + kb + col, (char*)Bh + flat * 16);
            gll16(Mt_lo + (size_t)(b * 256 + col0 + row) * 512 + kb + col, (char*)Bl + flat * 16);
        }
        __syncthreads();
#pragma unroll
        for (int ks = 0; ks < 2; ks++) {
            bf16x8 af[4], bh4[4], bl4[4];
#pragma unroll
            for (int r = 0; r < 4; r++)
                af[r] = *(const bf16x8*)&A[(wm * 64 + r * 16 + l15) * 64 + ks * 32 + quad * 8];
#pragma unroll
            for (int c = 0; c < 4; c++) {
                bh4[c] = *(const bf16x8*)&Bh[(wn * 64 + c * 16 + l15) * 64 + ks * 32 + quad * 8];
                bl4[c] = *(const bf16x8*)&Bl[(wn * 64 + c * 16 + l15) * 64 + ks * 32 + quad * 8];
            }
#pragma unroll
            for (int r = 0; r < 4; r++)
#pragma unroll
                for (int c = 0; c < 4; c++) {
                    acc[r][c] = __builtin_amdgcn_mfma_f32_16x16x32_bf16(af[r], bh4[c], acc[r][c], 0, 0, 0);
                    acc[r][c] = __builtin_amdgcn_mfma_f32_16x16x32_bf16(af[r], bl4[c], acc[r][c], 0, 0, 0);
                }
        }
    }
    float biasc[4];
#pragma unroll
    for (int c = 0; c < 4; c++) biasc[c] = bout[col0 + wn * 64 + c * 16 + l15];
#pragma unroll
    for (int r = 0; r < 4; r++)
#pragma unroll
        for (int c = 0; c < 4; c++)
#pragma unroll
            for (int j = 0; j < 4; j++)
                out[(size_t)(m0 + wm * 64 + r * 16 + quad * 4 + j) * 256 + col0 + wn * 64 + c * 16 + l15] =
                    acc[r][c][j] + biasc[c];
}

// ---------------------------------------------------------------------------
extern "C" void kernel_launch(void* const* d_in, const int* in_sizes, int n_in,
                              void* d_out, int out_size, void* d_ws, size_t ws_size,
                              hipStream_t stream) {
    const float* x    = (const float*)d_in[0];
    const float* Wfx  = (const float*)d_in[1];
    const float* bfx  = (const float*)d_in[2];
    const float* Wx   = (const float*)d_in[3];
    const float* bx   = (const float*)d_in[4];
    const float* Wsl  = (const float*)d_in[5];
    const float* bsl  = (const float*)d_in[6];
    const float* temp = (const float*)d_in[7];
    const float* Wq   = (const float*)d_in[8];
    const float* Wk   = (const float*)d_in[9];
    const float* Wv   = (const float*)d_in[10];
    const float* Wout = (const float*)d_in[11];
    const float* bout = (const float*)d_in[12];
    float* out = (float*)d_out;

    const int Mtotal = in_sizes[0] / DIM;   // 131072
    const int B = Mtotal / NPTS;            // 4

    // workspace layout (~272 MB peak — matches R1's proven footprint)
    char* p = (char*)d_ws;
    unsigned short* Wbt   = (unsigned short*)p; p += (size_t)1024 * 256 * 2;          // 512 KB
    unsigned short* WslTg = (unsigned short*)p; p += (size_t)64 * 64 * 2;             // 8 KB
    unsigned short* fxT   = (unsigned short*)p; p += (size_t)Mtotal * INNER * 2;      // 134 MB (reused as wN)
    unsigned short* wT    = (unsigned short*)p; p += (size_t)Mtotal * INNER * 2;      // 134 MB
    float* token_num = (float*)p; p += (size_t)B * 8 * 64 * 64 * 4;                   // 512 KB
    float* norm_ws   = (float*)p; p += (size_t)B * 8 * 64 * 4;                        // 8 KB
    float* os_ws     = (float*)p; p += (size_t)B * 8 * 64 * 64 * 4;                   // 512 KB
    unsigned short* Mt_hi = (unsigned short*)p; p += (size_t)B * 256 * 512 * 2;       // 1 MB
    unsigned short* Mt_lo = (unsigned short*)p; p += (size_t)B * 256 * 512 * 2;       // 1 MB
    unsigned short* wN = fxT;  // alias: k_tr writes after k_pool consumed fxT

    // zero split-K accumulators (token_num + norm contiguous)
    hipMemsetAsync(token_num, 0,
                   (size_t)B * 8 * 64 * 64 * 4 + (size_t)B * 8 * 64 * 4, stream);

    k_prep<<<5, 256, 0, stream>>>(Wfx, Wx, Wsl, Wbt, WslTg);
    k_proj<<<dim3(8, Mtotal / 128), 256, 0, stream>>>(
        x, Wbt, bfx, bx, WslTg, bsl, temp, fxT, wT, norm_ws);
    k_pool<<<dim3(POOL_SPLIT, 8, B), 256, 0, stream>>>(wT, fxT, token_num);
    k_attn<<<B * 8, 256, 0, stream>>>(token_num, norm_ws, Wq, Wk, Wv, os_ws);
    k_tr<<<dim3(NPTS / 256, 8, B), 256, 0, stream>>>(wT, wN);
    k_m<<<dim3(8, B), 256, 0, stream>>>(os_ws, Wout, Mt_hi, Mt_lo);
    k_out<<<dim3(2, Mtotal / 128), 256, 0, stream>>>(wN, Mt_hi, Mt_lo, bout, out);
}

// Round 4
// 840.216 us; speedup vs baseline: 2.7636x; 1.0453x over previous
//
#include <hip/hip_runtime.h>
#include <hip/hip_bf16.h>
#include <stdint.h>

#define DIM 256
#define HEADS 8
#define INNER 512
#define NPTS 32768
#define PADN 136   // wsmT/fxS row pad in shorts (16B-aligned rows, 2-way-free b128 reads)
#define PADD 72    // xm row pad in shorts

typedef unsigned int uint32;
typedef short bf16x8 __attribute__((ext_vector_type(8)));
typedef float f32x4 __attribute__((ext_vector_type(4)));

static __device__ __forceinline__ unsigned short f2bf(float f) {
    unsigned int u = __float_as_uint(f);
    u += 0x7fffu + ((u >> 16) & 1u);   // RNE
    return (unsigned short)(u >> 16);
}
static __device__ __forceinline__ float bf2f(unsigned short v) {
    return __uint_as_float(((unsigned int)v) << 16);
}
static __device__ __forceinline__ uint32 pkbf(float a, float b) {
    __hip_bfloat162 h = __float22bfloat162_rn(make_float2(a, b));
    return *(reinterpret_cast<uint32*>(&h));
}
static __device__ __forceinline__ void gll16(const void* g, const void* l) {
    __builtin_amdgcn_global_load_lds(
        (const __attribute__((address_space(1))) uint32*)g,
        (__attribute__((address_space(3))) uint32*)l, 16, 0, 0);
}

// ---------------------------------------------------------------------------
// K0: prep — Wfx|Wx -> combined transposed bf16 [1024][256]; Wsl -> [g][d]
// ---------------------------------------------------------------------------
__global__ __launch_bounds__(256) void k_prep(
    const float* __restrict__ Wfx, const float* __restrict__ Wx,
    const float* __restrict__ Wsl,
    unsigned short* __restrict__ Wbt, unsigned short* __restrict__ WslT)
{
    const int blk = blockIdx.x, t = threadIdx.x;
    if (blk < 4) {
        const int n = blk * 256 + t;
        for (int k8 = 0; k8 < 256; k8 += 8) {
            unsigned short v[8];
#pragma unroll
            for (int j = 0; j < 8; j++) {
                float f = (n < 512) ? Wfx[(size_t)(k8 + j) * 512 + n]
                                    : Wx[(size_t)(k8 + j) * 512 + (n - 512)];
                v[j] = f2bf(f);
            }
            ushort4 u0 = {v[0], v[1], v[2], v[3]};
            ushort4 u1 = {v[4], v[5], v[6], v[7]};
            *(ushort4*)(Wbt + (size_t)n * 256 + k8) = u0;
            *(ushort4*)(Wbt + (size_t)n * 256 + k8 + 4) = u1;
        }
    } else {
        const int g = t >> 2, d0 = (t & 3) * 16;
        unsigned short v[16];
#pragma unroll
        for (int i = 0; i < 16; i++) v[i] = f2bf(Wsl[(size_t)(d0 + i) * 64 + g]);
#pragma unroll
        for (int q = 0; q < 4; q++) {
            ushort4 u = {v[q * 4], v[q * 4 + 1], v[q * 4 + 2], v[q * 4 + 3]};
            *(ushort4*)(WslT + (size_t)g * 64 + d0 + q * 4) = u;
        }
    }
}

// ---------------------------------------------------------------------------
// K1: mega-fused per-head kernel.
// grid (8 heads fast, 256 chunks). Each block: head h, 4 mtiles of 128 rows.
// Per mtile: GEMM x@[Wfx_h|Wx_h] (128x128x256) -> fx + x_mid; logits MFMA;
// softmax -> w; pooling MFMA accumulated in registers; wN written in final
// [n][h*64+g] layout. Block end: atomicAdd token partials + norm.
// Eliminates fxT/wT materialization, k_pool and k_tr entirely.
// ---------------------------------------------------------------------------
__global__ __launch_bounds__(256, 3) void k_projfused(
    const float* __restrict__ x,               // [M][256] fp32
    const unsigned short* __restrict__ Wbt,    // [1024][256] bf16
    const float* __restrict__ bfx, const float* __restrict__ bx,
    const unsigned short* __restrict__ WslTg,  // [64 g][64 d] bf16
    const float* __restrict__ bsl, const float* __restrict__ temp,
    unsigned short* __restrict__ wN,           // [b*n][512] bf16
    float* __restrict__ token_num,             // [b][h][64][64] fp32 (atomic)
    float* __restrict__ norm)                  // [b][h][64] fp32 (atomic)
{
    // S: staging A[128][64] + B[128][64] (16384 shorts); fxS[64][PADN] overlays S.
    // X: xm[128][PADD] (9216 shorts); wsmT[64][PADN] overlays X after logits.
    __shared__ unsigned short S[128 * 64 * 2];
    __shared__ unsigned short X[128 * PADD];

    const int h = blockIdx.x;
    const int chunk = blockIdx.y;          // 0..255
    const int b = chunk >> 6;              // 64 chunks per batch
    const int t = threadIdx.x;
    const int w = t >> 6, lane = t & 63;
    const int wm = w >> 1, wn = w & 1;
    const int l15 = lane & 15, quad = lane >> 4;

    unsigned short* A  = S;                // [128][64]
    unsigned short* Bs = S + 128 * 64;     // [128][64]
    unsigned short* fxS = S;               // [64][PADN] overlay
    unsigned short* wsmT = X;              // [64][PADN] overlay

    // W_slice B-fragments in registers (replaces LDS copy)
    bf16x8 wslf[4][2];
#pragma unroll
    for (int c = 0; c < 4; c++)
#pragma unroll
        for (int ks = 0; ks < 2; ks++)
            wslf[c][ks] = *(const bf16x8*)&WslTg[(c * 16 + l15) * 64 + ks * 32 + quad * 8];

    float tv = temp[h];
    tv = fminf(fmaxf(tv, 0.1f), 5.0f);
    const float itemp = 1.0f / tv;
    float bsl_c[4], bfx_c[4], bx_c[4];
#pragma unroll
    for (int c = 0; c < 4; c++) {
        bsl_c[c] = bsl[c * 16 + l15];
        bfx_c[c] = bfx[h * 64 + c * 16 + l15];
        bx_c[c]  = bx[h * 64 + c * 16 + l15];
    }

    f32x4 pacc[4];
#pragma unroll
    for (int c = 0; c < 4; c++) pacc[c] = (f32x4){0.f, 0.f, 0.f, 0.f};
    float ns[4] = {0.f, 0.f, 0.f, 0.f};

    for (int mt = 0; mt < 4; mt++) {
        const int n_in_b = ((chunk & 63) * 4 + mt) * 128;
        const size_t m0 = (size_t)b * NPTS + n_in_b;

        f32x4 acc[4][4];
#pragma unroll
        for (int r = 0; r < 4; r++)
#pragma unroll
            for (int c = 0; c < 4; c++) acc[r][c] = (f32x4){0.f, 0.f, 0.f, 0.f};

        for (int kb = 0; kb < 256; kb += 64) {
            float4 a0[4], a1[4];
#pragma unroll
            for (int rr = 0; rr < 4; rr++) {
                int flat = rr * 256 + t;
                int row = flat >> 3, colg = (flat & 7) * 8;
                const float* src = x + (m0 + row) * 256 + kb + colg;
                a0[rr] = *(const float4*)src;
                a1[rr] = *(const float4*)(src + 4);
            }
            __syncthreads();
#pragma unroll
            for (int rr = 0; rr < 4; rr++) {
                int flat = rr * 256 + t;
                int row = flat >> 3, colg = (flat & 7) * 8;
                int grow = (rr < 2) ? (h * 64 + row) : (512 + h * 64 + (row - 64));
                gll16(Wbt + (size_t)grow * 256 + kb + colg, (char*)Bs + flat * 16);
            }
#pragma unroll
            for (int rr = 0; rr < 4; rr++) {
                int flat = rr * 256 + t;
                int row = flat >> 3, colg = (flat & 7) * 8;
                uint4 v;
                v.x = pkbf(a0[rr].x, a0[rr].y);
                v.y = pkbf(a0[rr].z, a0[rr].w);
                v.z = pkbf(a1[rr].x, a1[rr].y);
                v.w = pkbf(a1[rr].z, a1[rr].w);
                *(uint4*)&A[row * 64 + colg] = v;
            }
            __syncthreads();
#pragma unroll
            for (int ks = 0; ks < 2; ks++) {
                bf16x8 af[4], bfv[4];
#pragma unroll
                for (int r = 0; r < 4; r++)
                    af[r] = *(const bf16x8*)&A[(wm * 64 + r * 16 + l15) * 64 + ks * 32 + quad * 8];
#pragma unroll
                for (int c = 0; c < 4; c++)
                    bfv[c] = *(const bf16x8*)&Bs[(wn * 64 + c * 16 + l15) * 64 + ks * 32 + quad * 8];
#pragma unroll
                for (int r = 0; r < 4; r++)
#pragma unroll
                    for (int c = 0; c < 4; c++)
                        acc[r][c] = __builtin_amdgcn_mfma_f32_16x16x32_bf16(af[r], bfv[c], acc[r][c], 0, 0, 0);
            }
        }

        // ---- epilogue: fx -> fxS (wn==0 waves), x_mid -> xm (wn==1 waves) ----
        __syncthreads();
        if (wn == 0) {
#pragma unroll
            for (int r = 0; r < 4; r++)
#pragma unroll
                for (int c = 0; c < 4; c++) {
                    ushort4 u;
                    u.x = f2bf(acc[r][c][0] + bfx_c[c]);
                    u.y = f2bf(acc[r][c][1] + bfx_c[c]);
                    u.z = f2bf(acc[r][c][2] + bfx_c[c]);
                    u.w = f2bf(acc[r][c][3] + bfx_c[c]);
                    *(ushort4*)&fxS[(c * 16 + l15) * PADN + wm * 64 + r * 16 + quad * 4] = u;
                }
        } else {
#pragma unroll
            for (int r = 0; r < 4; r++)
#pragma unroll
                for (int c = 0; c < 4; c++)
#pragma unroll
                    for (int j = 0; j < 4; j++)
                        X[(wm * 64 + r * 16 + quad * 4 + j) * PADD + c * 16 + l15] =
                            f2bf(acc[r][c][j] + bx_c[c]);
        }
        __syncthreads();

        // ---- logits MFMA: 128 rows x 64 g, K=64. wave w -> rows w*32..+31 ----
        f32x4 lacc[2][4];
#pragma unroll
        for (int rt = 0; rt < 2; rt++)
#pragma unroll
            for (int c = 0; c < 4; c++)
                lacc[rt][c] = (f32x4){bsl_c[c], bsl_c[c], bsl_c[c], bsl_c[c]};
#pragma unroll
        for (int ks = 0; ks < 2; ks++) {
            bf16x8 laf[2];
#pragma unroll
            for (int rt = 0; rt < 2; rt++)
                laf[rt] = *(const bf16x8*)&X[(w * 32 + rt * 16 + l15) * PADD + ks * 32 + quad * 8];
#pragma unroll
            for (int rt = 0; rt < 2; rt++)
#pragma unroll
                for (int c = 0; c < 4; c++)
                    lacc[rt][c] = __builtin_amdgcn_mfma_f32_16x16x32_bf16(laf[rt], wslf[c][ks], lacc[rt][c], 0, 0, 0);
        }
        __syncthreads();   // xm dead -> wsmT overlays X

        // ---- softmax over g; w -> wsmT[g][n]; ns accumulation ----
#pragma unroll
        for (int rt = 0; rt < 2; rt++) {
            float wv[4][4];
#pragma unroll
            for (int j = 0; j < 4; j++) {
                float v0 = lacc[rt][0][j] * itemp;
                float v1 = lacc[rt][1][j] * itemp;
                float v2 = lacc[rt][2][j] * itemp;
                float v3 = lacc[rt][3][j] * itemp;
                float mx = fmaxf(fmaxf(v0, v1), fmaxf(v2, v3));
                mx = fmaxf(mx, __shfl_xor(mx, 1));
                mx = fmaxf(mx, __shfl_xor(mx, 2));
                mx = fmaxf(mx, __shfl_xor(mx, 4));
                mx = fmaxf(mx, __shfl_xor(mx, 8));
                float e0 = __expf(v0 - mx), e1 = __expf(v1 - mx);
                float e2 = __expf(v2 - mx), e3 = __expf(v3 - mx);
                float s = e0 + e1 + e2 + e3;
                s += __shfl_xor(s, 1);
                s += __shfl_xor(s, 2);
                s += __shfl_xor(s, 4);
                s += __shfl_xor(s, 8);
                float inv = 1.0f / s;
                wv[0][j] = e0 * inv; wv[1][j] = e1 * inv;
                wv[2][j] = e2 * inv; wv[3][j] = e3 * inv;
                ns[0] += wv[0][j]; ns[1] += wv[1][j];
                ns[2] += wv[2][j]; ns[3] += wv[3][j];
            }
#pragma unroll
            for (int c = 0; c < 4; c++) {
                ushort4 u;
                u.x = f2bf(wv[c][0]); u.y = f2bf(wv[c][1]);
                u.z = f2bf(wv[c][2]); u.w = f2bf(wv[c][3]);
                *(ushort4*)&wsmT[(c * 16 + l15) * PADN + w * 32 + rt * 16 + quad * 4] = u;
            }
        }
        __syncthreads();

        // ---- pooling MFMA: token[g][d] += w^T @ fx^T, K=128. wave w -> g rows w*16..+15
#pragma unroll
        for (int kk = 0; kk < 4; kk++) {
            bf16x8 paf = *(const bf16x8*)&wsmT[(w * 16 + l15) * PADN + kk * 32 + quad * 8];
#pragma unroll
            for (int c = 0; c < 4; c++) {
                bf16x8 pbf = *(const bf16x8*)&fxS[(c * 16 + l15) * PADN + kk * 32 + quad * 8];
                pacc[c] = __builtin_amdgcn_mfma_f32_16x16x32_bf16(paf, pbf, pacc[c], 0, 0, 0);
            }
        }

        // ---- wN write: [n][h*64+g], 64B contiguous per thread ----
        {
            const int n = t >> 1, half = t & 1;
            unsigned short* dst = wN + ((size_t)b * NPTS + n_in_b + n) * 512 + h * 64 + half * 32;
#pragma unroll
            for (int g4 = 0; g4 < 8; g4++) {
                ushort4 u;
                u.x = wsmT[(half * 32 + g4 * 4 + 0) * PADN + n];
                u.y = wsmT[(half * 32 + g4 * 4 + 1) * PADN + n];
                u.z = wsmT[(half * 32 + g4 * 4 + 2) * PADN + n];
                u.w = wsmT[(half * 32 + g4 * 4 + 3) * PADN + n];
                *(ushort4*)(dst + g4 * 4) = u;
            }
        }
        // loop-top __syncthreads() protects staging overwrite of fxS/wsmT
    }

    // ---- block-end atomics: token partials + norm ----
    float* tn = token_num + ((size_t)(b * 8 + h) * 64) * 64;
#pragma unroll
    for (int c = 0; c < 4; c++)
#pragma unroll
        for (int j = 0; j < 4; j++)
            atomicAdd(tn + (size_t)(w * 16 + quad * 4 + j) * 64 + c * 16 + l15, pacc[c][j]);
#pragma unroll
    for (int c = 0; c < 4; c++) {
        ns[c] += __shfl_xor(ns[c], 16);
        ns[c] += __shfl_xor(ns[c], 32);
    }
    if (quad == 0) {
#pragma unroll
        for (int c = 0; c < 4; c++)
            atomicAdd(norm + ((size_t)b * 8 + h) * 64 + c * 16 + l15, ns[c]);
    }
}

// ---------------------------------------------------------------------------
// K3: tiny attention over 64 slice tokens per (b,h). (unchanged; proven)
// ---------------------------------------------------------------------------
__global__ __launch_bounds__(256) void k_attn(
    const float* __restrict__ token_num, const float* __restrict__ norm,
    const float* __restrict__ Wq, const float* __restrict__ Wk,
    const float* __restrict__ Wv, float* __restrict__ out_slice)
{
    const int bh = blockIdx.x;
    const int t = threadIdx.x;
    const int gg = t >> 2, qq = t & 3;

    __shared__ float tok[64][68];
    __shared__ float qS[64][68];
    __shared__ float kS[64][68];
    __shared__ float vS[64][68];
    __shared__ float pS[64][68];
    __shared__ float Wqs[64][64], Wks[64][64], Wvs[64][64];

    for (int i = t; i < 4096; i += 256) {
        int g = i >> 6, dd = i & 63;
        Wqs[g][dd] = Wq[i];
        Wks[g][dd] = Wk[i];
        Wvs[g][dd] = Wv[i];
        tok[g][dd] = token_num[(size_t)bh * 4096 + i] / (norm[bh * 64 + g] + 1e-5f);
    }
    __syncthreads();

    float aq[16] = {}, ak[16] = {}, av[16] = {};
    for (int k = 0; k < 64; k++) {
        const float tv = tok[gg][k];
        const float4* wq4 = (const float4*)&Wqs[k][qq * 16];
        const float4* wk4 = (const float4*)&Wks[k][qq * 16];
        const float4* wv4 = (const float4*)&Wvs[k][qq * 16];
#pragma unroll
        for (int j4 = 0; j4 < 4; j4++) {
            float4 a = wq4[j4], bq = wk4[j4], c = wv4[j4];
            aq[j4*4+0] = fmaf(tv, a.x,  aq[j4*4+0]);
            aq[j4*4+1] = fmaf(tv, a.y,  aq[j4*4+1]);
            aq[j4*4+2] = fmaf(tv, a.z,  aq[j4*4+2]);
            aq[j4*4+3] = fmaf(tv, a.w,  aq[j4*4+3]);
            ak[j4*4+0] = fmaf(tv, bq.x, ak[j4*4+0]);
            ak[j4*4+1] = fmaf(tv, bq.y, ak[j4*4+1]);
            ak[j4*4+2] = fmaf(tv, bq.z, ak[j4*4+2]);
            ak[j4*4+3] = fmaf(tv, bq.w, ak[j4*4+3]);
            av[j4*4+0] = fmaf(tv, c.x,  av[j4*4+0]);
            av[j4*4+1] = fmaf(tv, c.y,  av[j4*4+1]);
            av[j4*4+2] = fmaf(tv, c.z,  av[j4*4+2]);
            av[j4*4+3] = fmaf(tv, c.w,  av[j4*4+3]);
        }
    }
#pragma unroll
    for (int j = 0; j < 16; j++) {
        qS[gg][qq * 16 + j] = aq[j];
        kS[gg][qq * 16 + j] = ak[j];
        vS[gg][qq * 16 + j] = av[j];
    }
    __syncthreads();

    float sc[16] = {};
    for (int d4 = 0; d4 < 16; d4++) {
        float4 q4 = *(const float4*)&qS[gg][d4 * 4];
#pragma unroll
        for (int j = 0; j < 16; j++) {
            float4 k4 = *(const float4*)&kS[qq * 16 + j][d4 * 4];
            sc[j] = fmaf(q4.x, k4.x, sc[j]);
            sc[j] = fmaf(q4.y, k4.y, sc[j]);
            sc[j] = fmaf(q4.z, k4.z, sc[j]);
            sc[j] = fmaf(q4.w, k4.w, sc[j]);
        }
    }
    const float SCALE = 0.125f;
    float mx = -1e30f;
#pragma unroll
    for (int j = 0; j < 16; j++) { sc[j] *= SCALE; mx = fmaxf(mx, sc[j]); }
    mx = fmaxf(mx, __shfl_xor(mx, 1));
    mx = fmaxf(mx, __shfl_xor(mx, 2));
    float s = 0.f;
#pragma unroll
    for (int j = 0; j < 16; j++) { sc[j] = __expf(sc[j] - mx); s += sc[j]; }
    s += __shfl_xor(s, 1);
    s += __shfl_xor(s, 2);
    const float invs = 1.0f / s;
#pragma unroll
    for (int j = 0; j < 16; j++) pS[gg][qq * 16 + j] = sc[j] * invs;
    __syncthreads();

    float oo[16] = {};
    for (int j = 0; j < 64; j++) {
        const float pv = pS[gg][j];
        const float4* v4p = (const float4*)&vS[j][qq * 16];
#pragma unroll
        for (int d4 = 0; d4 < 4; d4++) {
            float4 v4 = v4p[d4];
            oo[d4*4+0] = fmaf(pv, v4.x, oo[d4*4+0]);
            oo[d4*4+1] = fmaf(pv, v4.y, oo[d4*4+1]);
            oo[d4*4+2] = fmaf(pv, v4.z, oo[d4*4+2]);
            oo[d4*4+3] = fmaf(pv, v4.w, oo[d4*4+3]);
        }
    }
    float* op = out_slice + (size_t)bh * 4096 + gg * 64 + qq * 16;
#pragma unroll
    for (int d4 = 0; d4 < 4; d4++) {
        float4 o; o.x = oo[d4*4+0]; o.y = oo[d4*4+1]; o.z = oo[d4*4+2]; o.w = oo[d4*4+3];
        *(float4*)(op + d4 * 4) = o;
    }
}

// ---------------------------------------------------------------------------
// K5: Mt[c][hg] = sum_d os[b][h][g][d] * W_out[h*64+d][c], split hi/lo bf16
// ---------------------------------------------------------------------------
__global__ __launch_bounds__(256) void k_m(
    const float* __restrict__ os, const float* __restrict__ W_out,
    unsigned short* __restrict__ Mt_hi, unsigned short* __restrict__ Mt_lo)
{
    const int h = blockIdx.x, b = blockIdx.y;
    const int t = threadIdx.x;   // c
    __shared__ float osl[64][65];
    for (int i = t; i < 4096; i += 256)
        osl[i >> 6][i & 63] = os[(size_t)(b * 8 + h) * 4096 + i];
    __syncthreads();
    float acc[64];
#pragma unroll
    for (int g = 0; g < 64; g++) acc[g] = 0.f;
    for (int d = 0; d < 64; d++) {
        float wv = W_out[(size_t)(h * 64 + d) * 256 + t];
#pragma unroll
        for (int g = 0; g < 64; g++) acc[g] = fmaf(osl[g][d], wv, acc[g]);
    }
    unsigned short* ph = Mt_hi + (size_t)(b * 256 + t) * 512 + h * 64;
    unsigned short* pl = Mt_lo + (size_t)(b * 256 + t) * 512 + h * 64;
#pragma unroll
    for (int g4 = 0; g4 < 16; g4++) {
        ushort4 uh, ul;
        unsigned short hh; float v, lo;
        v = acc[g4*4+0]; hh = f2bf(v); lo = v - bf2f(hh); uh.x = hh; ul.x = f2bf(lo);
        v = acc[g4*4+1]; hh = f2bf(v); lo = v - bf2f(hh); uh.y = hh; ul.y = f2bf(lo);
        v = acc[g4*4+2]; hh = f2bf(v); lo = v - bf2f(hh); uh.z = hh; ul.z = f2bf(lo);
        v = acc[g4*4+3]; hh = f2bf(v); lo = v - bf2f(hh); uh.w = hh; ul.w = f2bf(lo);
        *(ushort4*)(ph + g4 * 4) = uh;
        *(ushort4*)(pl + g4 * 4) = ul;
    }
}

// ---------------------------------------------------------------------------
// K6: out[m][c] = sum_k wN[m][k] * (Mt_hi+Mt_lo)[c][k] + bout[c]   (MFMA)
// ---------------------------------------------------------------------------
__global__ __launch_bounds__(256, 3) void k_out(
    const unsigned short* __restrict__ wN,
    const unsigned short* __restrict__ Mt_hi, const unsigned short* __restrict__ Mt_lo,
    const float* __restrict__ bout, float* __restrict__ out)
{
    __shared__ unsigned short A[128 * 64];
    __shared__ unsigned short Bh[128 * 64];
    __shared__ unsigned short Bl[128 * 64];
    const int ntile = blockIdx.x;   // 0..1
    const int mtile = blockIdx.y;
    const int m0 = mtile * 128, col0 = ntile * 128;
    const int b = m0 >> 15;
    const int t = threadIdx.x;
    const int w = t >> 6, lane = t & 63, l15 = lane & 15, quad = lane >> 4;
    const int wm = w >> 1, wn = w & 1;

    f32x4 acc[4][4];
#pragma unroll
    for (int r = 0; r < 4; r++)
#pragma unroll
        for (int c = 0; c < 4; c++) acc[r][c] = (f32x4){0.f, 0.f, 0.f, 0.f};

    for (int kb = 0; kb < 512; kb += 64) {
        __syncthreads();
#pragma unroll
        for (int rr = 0; rr < 4; rr++) {
            int flat = rr * 256 + t;
            int row = flat >> 3, col = (flat & 7) * 8;
            gll16(wN + (size_t)(m0 + row) * 512 + kb + col, (char*)A + flat * 16);
            gll16(Mt_hi + (size_t)(b * 256 + col0 + row) * 512 + kb + col, (char*)Bh + flat * 16);
            gll16(Mt_lo + (size_t)(b * 256 + col0 + row) * 512 + kb + col, (char*)Bl + flat * 16);
        }
        __syncthreads();
#pragma unroll
        for (int ks = 0; ks < 2; ks++) {
            bf16x8 af[4], bh4[4], bl4[4];
#pragma unroll
            for (int r = 0; r < 4; r++)
                af[r] = *(const bf16x8*)&A[(wm * 64 + r * 16 + l15) * 64 + ks * 32 + quad * 8];
#pragma unroll
            for (int c = 0; c < 4; c++) {
                bh4[c] = *(const bf16x8*)&Bh[(wn * 64 + c * 16 + l15) * 64 + ks * 32 + quad * 8];
                bl4[c] = *(const bf16x8*)&Bl[(wn * 64 + c * 16 + l15) * 64 + ks * 32 + quad * 8];
            }
#pragma unroll
            for (int r = 0; r < 4; r++)
#pragma unroll
                for (int c = 0; c < 4; c++) {
                    acc[r][c] = __builtin_amdgcn_mfma_f32_16x16x32_bf16(af[r], bh4[c], acc[r][c], 0, 0, 0);
                    acc[r][c] = __builtin_amdgcn_mfma_f32_16x16x32_bf16(af[r], bl4[c], acc[r][c], 0, 0, 0);
                }
        }
    }
    float biasc[4];
#pragma unroll
    for (int c = 0; c < 4; c++) biasc[c] = bout[col0 + wn * 64 + c * 16 + l15];
#pragma unroll
    for (int r = 0; r < 4; r++)
#pragma unroll
        for (int c = 0; c < 4; c++)
#pragma unroll
            for (int j = 0; j < 4; j++)
                out[(size_t)(m0 + wm * 64 + r * 16 + quad * 4 + j) * 256 + col0 + wn * 64 + c * 16 + l15] =
                    acc[r][c][j] + biasc[c];
}

// ---------------------------------------------------------------------------
extern "C" void kernel_launch(void* const* d_in, const int* in_sizes, int n_in,
                              void* d_out, int out_size, void* d_ws, size_t ws_size,
                              hipStream_t stream) {
    const float* x    = (const float*)d_in[0];
    const float* Wfx  = (const float*)d_in[1];
    const float* bfx  = (const float*)d_in[2];
    const float* Wx   = (const float*)d_in[3];
    const float* bx   = (const float*)d_in[4];
    const float* Wsl  = (const float*)d_in[5];
    const float* bsl  = (const float*)d_in[6];
    const float* temp = (const float*)d_in[7];
    const float* Wq   = (const float*)d_in[8];
    const float* Wk   = (const float*)d_in[9];
    const float* Wv   = (const float*)d_in[10];
    const float* Wout = (const float*)d_in[11];
    const float* bout = (const float*)d_in[12];
    float* out = (float*)d_out;

    const int Mtotal = in_sizes[0] / DIM;   // 131072
    const int B = Mtotal / NPTS;            // 4

    // workspace (~138 MB peak)
    char* p = (char*)d_ws;
    unsigned short* Wbt   = (unsigned short*)p; p += (size_t)1024 * 256 * 2;        // 512 KB
    unsigned short* WslTg = (unsigned short*)p; p += (size_t)64 * 64 * 2;           // 8 KB
    unsigned short* wN    = (unsigned short*)p; p += (size_t)Mtotal * INNER * 2;    // 134 MB
    float* token_num = (float*)p; p += (size_t)B * 8 * 64 * 64 * 4;                 // 512 KB
    float* norm_ws   = (float*)p; p += (size_t)B * 8 * 64 * 4;                      // 8 KB
    float* os_ws     = (float*)p; p += (size_t)B * 8 * 64 * 64 * 4;                 // 512 KB
    unsigned short* Mt_hi = (unsigned short*)p; p += (size_t)B * 256 * 512 * 2;     // 1 MB
    unsigned short* Mt_lo = (unsigned short*)p; p += (size_t)B * 256 * 512 * 2;     // 1 MB

    // zero atomic accumulators (token_num + norm contiguous)
    hipMemsetAsync(token_num, 0,
                   (size_t)B * 8 * 64 * 64 * 4 + (size_t)B * 8 * 64 * 4, stream);

    k_prep<<<5, 256, 0, stream>>>(Wfx, Wx, Wsl, Wbt, WslTg);
    k_projfused<<<dim3(8, (Mtotal / 128) / 4), 256, 0, stream>>>(
        x, Wbt, bfx, bx, WslTg, bsl, temp, wN, token_num, norm_ws);
    k_attn<<<B * 8, 256, 0, stream>>>(token_num, norm_ws, Wq, Wk, Wv, os_ws);
    k_m<<<dim3(8, B), 256, 0, stream>>>(os_ws, Wout, Mt_hi, Mt_lo);
    k_out<<<dim3(2, Mtotal / 128), 256, 0, stream>>>(wN, Mt_hi, Mt_lo, bout, out);
}

// Round 5
// 825.516 us; speedup vs baseline: 2.8128x; 1.0178x over previous
//
#include <hip/hip_runtime.h>
#include <hip/hip_bf16.h>
#include <stdint.h>

#define DIM 256
#define HEADS 8
#define INNER 512
#define NPTS 32768
#define PADN 136   // wsmT/fxS row pad in shorts (16B-aligned rows)
#define PADD 72    // xm row pad in shorts

typedef unsigned int uint32;
typedef short bf16x8 __attribute__((ext_vector_type(8)));
typedef float f32x4 __attribute__((ext_vector_type(4)));

static __device__ __forceinline__ unsigned short f2bf(float f) {
    unsigned int u = __float_as_uint(f);
    u += 0x7fffu + ((u >> 16) & 1u);   // RNE
    return (unsigned short)(u >> 16);
}
static __device__ __forceinline__ float bf2f(unsigned short v) {
    return __uint_as_float(((unsigned int)v) << 16);
}
static __device__ __forceinline__ uint32 pkbf(float a, float b) {
    __hip_bfloat162 h = __float22bfloat162_rn(make_float2(a, b));
    return *(reinterpret_cast<uint32*>(&h));
}
static __device__ __forceinline__ void gll16(const void* g, const void* l) {
    __builtin_amdgcn_global_load_lds(
        (const __attribute__((address_space(1))) uint32*)g,
        (__attribute__((address_space(3))) uint32*)l, 16, 0, 0);
}

// ---------------------------------------------------------------------------
// K0: prep — Wfx|Wx -> combined transposed bf16 [1024][256]; Wsl -> [g][d]
// ---------------------------------------------------------------------------
__global__ __launch_bounds__(256) void k_prep(
    const float* __restrict__ Wfx, const float* __restrict__ Wx,
    const float* __restrict__ Wsl,
    unsigned short* __restrict__ Wbt, unsigned short* __restrict__ WslT)
{
    const int blk = blockIdx.x, t = threadIdx.x;
    if (blk < 4) {
        const int n = blk * 256 + t;
        for (int k8 = 0; k8 < 256; k8 += 8) {
            unsigned short v[8];
#pragma unroll
            for (int j = 0; j < 8; j++) {
                float f = (n < 512) ? Wfx[(size_t)(k8 + j) * 512 + n]
                                    : Wx[(size_t)(k8 + j) * 512 + (n - 512)];
                v[j] = f2bf(f);
            }
            ushort4 u0 = {v[0], v[1], v[2], v[3]};
            ushort4 u1 = {v[4], v[5], v[6], v[7]};
            *(ushort4*)(Wbt + (size_t)n * 256 + k8) = u0;
            *(ushort4*)(Wbt + (size_t)n * 256 + k8 + 4) = u1;
        }
    } else {
        const int g = t >> 2, d0 = (t & 3) * 16;
        unsigned short v[16];
#pragma unroll
        for (int i = 0; i < 16; i++) v[i] = f2bf(Wsl[(size_t)(d0 + i) * 64 + g]);
#pragma unroll
        for (int q = 0; q < 4; q++) {
            ushort4 u = {v[q * 4], v[q * 4 + 1], v[q * 4 + 2], v[q * 4 + 3]};
            *(ushort4*)(WslT + (size_t)g * 64 + d0 + q * 4) = u;
        }
    }
}

// ---------------------------------------------------------------------------
// K1: mega-fused per-head kernel (1-D grid 2048, XCD-affinity swizzle).
// xcd = L&7; all 8 heads of a chunk land on the same XCD so the shared
// x-tile is fetched into that XCD's L2 once, not 8x (R4: FETCH was 7x of x).
// ---------------------------------------------------------------------------
__global__ __launch_bounds__(256, 3) void k_projfused(
    const float* __restrict__ x,               // [M][256] fp32
    const unsigned short* __restrict__ Wbt,    // [1024][256] bf16
    const float* __restrict__ bfx, const float* __restrict__ bx,
    const unsigned short* __restrict__ WslTg,  // [64 g][64 d] bf16
    const float* __restrict__ bsl, const float* __restrict__ temp,
    unsigned short* __restrict__ wN,           // [b*n][512] bf16
    float* __restrict__ token_num,             // [b][h][64][64] fp32 (atomic)
    float* __restrict__ norm)                  // [b][h][64] fp32 (atomic)
{
    __shared__ unsigned short S[128 * 64 * 2];   // A[128][64] + B[128][64]; fxS overlay
    __shared__ unsigned short X[128 * PADD];     // xm; wsmT overlay

    // XCD-affinity decode: blocks L with L%8==xcd serve chunks [xcd*32, xcd*32+32)
    const int L = blockIdx.x;
    const int xcd = L & 7;
    const int j = L >> 3;                  // 0..255
    const int chunk = xcd * 32 + (j >> 3); // 0..255
    const int h = j & 7;

    const int b = chunk >> 6;              // 64 chunks per batch
    const int t = threadIdx.x;
    const int w = t >> 6, lane = t & 63;
    const int wm = w >> 1, wn = w & 1;
    const int l15 = lane & 15, quad = lane >> 4;

    unsigned short* A  = S;                // [128][64]
    unsigned short* Bs = S + 128 * 64;     // [128][64]
    unsigned short* fxS = S;               // [64][PADN] overlay
    unsigned short* wsmT = X;              // [64][PADN] overlay

    bf16x8 wslf[4][2];
#pragma unroll
    for (int c = 0; c < 4; c++)
#pragma unroll
        for (int ks = 0; ks < 2; ks++)
            wslf[c][ks] = *(const bf16x8*)&WslTg[(c * 16 + l15) * 64 + ks * 32 + quad * 8];

    float tv = temp[h];
    tv = fminf(fmaxf(tv, 0.1f), 5.0f);
    const float itemp = 1.0f / tv;
    float bsl_c[4], bfx_c[4], bx_c[4];
#pragma unroll
    for (int c = 0; c < 4; c++) {
        bsl_c[c] = bsl[c * 16 + l15];
        bfx_c[c] = bfx[h * 64 + c * 16 + l15];
        bx_c[c]  = bx[h * 64 + c * 16 + l15];
    }

    f32x4 pacc[4];
#pragma unroll
    for (int c = 0; c < 4; c++) pacc[c] = (f32x4){0.f, 0.f, 0.f, 0.f};
    float ns[4] = {0.f, 0.f, 0.f, 0.f};

    for (int mt = 0; mt < 4; mt++) {
        const int n_in_b = ((chunk & 63) * 4 + mt) * 128;
        const size_t m0 = (size_t)b * NPTS + n_in_b;

        f32x4 acc[4][4];
#pragma unroll
        for (int r = 0; r < 4; r++)
#pragma unroll
            for (int c = 0; c < 4; c++) acc[r][c] = (f32x4){0.f, 0.f, 0.f, 0.f};

        for (int kb = 0; kb < 256; kb += 64) {
            float4 a0[4], a1[4];
#pragma unroll
            for (int rr = 0; rr < 4; rr++) {
                int flat = rr * 256 + t;
                int row = flat >> 3, colg = (flat & 7) * 8;
                const float* src = x + (m0 + row) * 256 + kb + colg;
                a0[rr] = *(const float4*)src;
                a1[rr] = *(const float4*)(src + 4);
            }
            __syncthreads();
#pragma unroll
            for (int rr = 0; rr < 4; rr++) {
                int flat = rr * 256 + t;
                int row = flat >> 3, colg = (flat & 7) * 8;
                int grow = (rr < 2) ? (h * 64 + row) : (512 + h * 64 + (row - 64));
                gll16(Wbt + (size_t)grow * 256 + kb + colg, (char*)Bs + flat * 16);
            }
#pragma unroll
            for (int rr = 0; rr < 4; rr++) {
                int flat = rr * 256 + t;
                int row = flat >> 3, colg = (flat & 7) * 8;
                uint4 v;
                v.x = pkbf(a0[rr].x, a0[rr].y);
                v.y = pkbf(a0[rr].z, a0[rr].w);
                v.z = pkbf(a1[rr].x, a1[rr].y);
                v.w = pkbf(a1[rr].z, a1[rr].w);
                *(uint4*)&A[row * 64 + colg] = v;
            }
            __syncthreads();
#pragma unroll
            for (int ks = 0; ks < 2; ks++) {
                bf16x8 af[4], bfv[4];
#pragma unroll
                for (int r = 0; r < 4; r++)
                    af[r] = *(const bf16x8*)&A[(wm * 64 + r * 16 + l15) * 64 + ks * 32 + quad * 8];
#pragma unroll
                for (int c = 0; c < 4; c++)
                    bfv[c] = *(const bf16x8*)&Bs[(wn * 64 + c * 16 + l15) * 64 + ks * 32 + quad * 8];
#pragma unroll
                for (int r = 0; r < 4; r++)
#pragma unroll
                    for (int c = 0; c < 4; c++)
                        acc[r][c] = __builtin_amdgcn_mfma_f32_16x16x32_bf16(af[r], bfv[c], acc[r][c], 0, 0, 0);
            }
        }

        // ---- epilogue: fx -> fxS (wn==0 waves), x_mid -> xm (wn==1 waves) ----
        __syncthreads();
        if (wn == 0) {
#pragma unroll
            for (int r = 0; r < 4; r++)
#pragma unroll
                for (int c = 0; c < 4; c++) {
                    ushort4 u;
                    u.x = f2bf(acc[r][c][0] + bfx_c[c]);
                    u.y = f2bf(acc[r][c][1] + bfx_c[c]);
                    u.z = f2bf(acc[r][c][2] + bfx_c[c]);
                    u.w = f2bf(acc[r][c][3] + bfx_c[c]);
                    *(ushort4*)&fxS[(c * 16 + l15) * PADN + wm * 64 + r * 16 + quad * 4] = u;
                }
        } else {
#pragma unroll
            for (int r = 0; r < 4; r++)
#pragma unroll
                for (int c = 0; c < 4; c++)
#pragma unroll
                    for (int j2 = 0; j2 < 4; j2++)
                        X[(wm * 64 + r * 16 + quad * 4 + j2) * PADD + c * 16 + l15] =
                            f2bf(acc[r][c][j2] + bx_c[c]);
        }
        __syncthreads();

        // ---- logits MFMA ----
        f32x4 lacc[2][4];
#pragma unroll
        for (int rt = 0; rt < 2; rt++)
#pragma unroll
            for (int c = 0; c < 4; c++)
                lacc[rt][c] = (f32x4){bsl_c[c], bsl_c[c], bsl_c[c], bsl_c[c]};
#pragma unroll
        for (int ks = 0; ks < 2; ks++) {
            bf16x8 laf[2];
#pragma unroll
            for (int rt = 0; rt < 2; rt++)
                laf[rt] = *(const bf16x8*)&X[(w * 32 + rt * 16 + l15) * PADD + ks * 32 + quad * 8];
#pragma unroll
            for (int rt = 0; rt < 2; rt++)
#pragma unroll
                for (int c = 0; c < 4; c++)
                    lacc[rt][c] = __builtin_amdgcn_mfma_f32_16x16x32_bf16(laf[rt], wslf[c][ks], lacc[rt][c], 0, 0, 0);
        }
        __syncthreads();   // xm dead -> wsmT overlays X

        // ---- softmax -> wsmT[g][n]; ns ----
#pragma unroll
        for (int rt = 0; rt < 2; rt++) {
            float wv[4][4];
#pragma unroll
            for (int j2 = 0; j2 < 4; j2++) {
                float v0 = lacc[rt][0][j2] * itemp;
                float v1 = lacc[rt][1][j2] * itemp;
                float v2 = lacc[rt][2][j2] * itemp;
                float v3 = lacc[rt][3][j2] * itemp;
                float mx = fmaxf(fmaxf(v0, v1), fmaxf(v2, v3));
                mx = fmaxf(mx, __shfl_xor(mx, 1));
                mx = fmaxf(mx, __shfl_xor(mx, 2));
                mx = fmaxf(mx, __shfl_xor(mx, 4));
                mx = fmaxf(mx, __shfl_xor(mx, 8));
                float e0 = __expf(v0 - mx), e1 = __expf(v1 - mx);
                float e2 = __expf(v2 - mx), e3 = __expf(v3 - mx);
                float s = e0 + e1 + e2 + e3;
                s += __shfl_xor(s, 1);
                s += __shfl_xor(s, 2);
                s += __shfl_xor(s, 4);
                s += __shfl_xor(s, 8);
                float inv = 1.0f / s;
                wv[0][j2] = e0 * inv; wv[1][j2] = e1 * inv;
                wv[2][j2] = e2 * inv; wv[3][j2] = e3 * inv;
                ns[0] += wv[0][j2]; ns[1] += wv[1][j2];
                ns[2] += wv[2][j2]; ns[3] += wv[3][j2];
            }
#pragma unroll
            for (int c = 0; c < 4; c++) {
                ushort4 u;
                u.x = f2bf(wv[c][0]); u.y = f2bf(wv[c][1]);
                u.z = f2bf(wv[c][2]); u.w = f2bf(wv[c][3]);
                *(ushort4*)&wsmT[(c * 16 + l15) * PADN + w * 32 + rt * 16 + quad * 4] = u;
            }
        }
        __syncthreads();

        // ---- pooling MFMA ----
#pragma unroll
        for (int kk = 0; kk < 4; kk++) {
            bf16x8 paf = *(const bf16x8*)&wsmT[(w * 16 + l15) * PADN + kk * 32 + quad * 8];
#pragma unroll
            for (int c = 0; c < 4; c++) {
                bf16x8 pbf = *(const bf16x8*)&fxS[(c * 16 + l15) * PADN + kk * 32 + quad * 8];
                pacc[c] = __builtin_amdgcn_mfma_f32_16x16x32_bf16(paf, pbf, pacc[c], 0, 0, 0);
            }
        }

        // ---- wN write: [n][h*64+g], 16-B stores ----
        {
            const int n = t >> 1, half = t & 1;
            unsigned short* dst = wN + ((size_t)b * NPTS + n_in_b + n) * 512 + h * 64 + half * 32;
#pragma unroll
            for (int g8 = 0; g8 < 4; g8++) {
                unsigned short tmp[8];
#pragma unroll
                for (int i = 0; i < 8; i++)
                    tmp[i] = wsmT[(half * 32 + g8 * 8 + i) * PADN + n];
                *(uint4*)(dst + g8 * 8) = *(const uint4*)tmp;
            }
        }
    }

    // ---- block-end atomics ----
    float* tn = token_num + ((size_t)(b * 8 + h) * 64) * 64;
#pragma unroll
    for (int c = 0; c < 4; c++)
#pragma unroll
        for (int j2 = 0; j2 < 4; j2++)
            atomicAdd(tn + (size_t)(w * 16 + quad * 4 + j2) * 64 + c * 16 + l15, pacc[c][j2]);
#pragma unroll
    for (int c = 0; c < 4; c++) {
        ns[c] += __shfl_xor(ns[c], 16);
        ns[c] += __shfl_xor(ns[c], 32);
    }
    if (quad == 0) {
#pragma unroll
        for (int c = 0; c < 4; c++)
            atomicAdd(norm + ((size_t)b * 8 + h) * 64 + c * 16 + l15, ns[c]);
    }
}

// ---------------------------------------------------------------------------
// K3: tiny attention over 64 slice tokens per (b,h). (unchanged; proven)
// ---------------------------------------------------------------------------
__global__ __launch_bounds__(256) void k_attn(
    const float* __restrict__ token_num, const float* __restrict__ norm,
    const float* __restrict__ Wq, const float* __restrict__ Wk,
    const float* __restrict__ Wv, float* __restrict__ out_slice)
{
    const int bh = blockIdx.x;
    const int t = threadIdx.x;
    const int gg = t >> 2, qq = t & 3;

    __shared__ float tok[64][68];
    __shared__ float qS[64][68];
    __shared__ float kS[64][68];
    __shared__ float vS[64][68];
    __shared__ float pS[64][68];
    __shared__ float Wqs[64][64], Wks[64][64], Wvs[64][64];

    for (int i = t; i < 4096; i += 256) {
        int g = i >> 6, dd = i & 63;
        Wqs[g][dd] = Wq[i];
        Wks[g][dd] = Wk[i];
        Wvs[g][dd] = Wv[i];
        tok[g][dd] = token_num[(size_t)bh * 4096 + i] / (norm[bh * 64 + g] + 1e-5f);
    }
    __syncthreads();

    float aq[16] = {}, ak[16] = {}, av[16] = {};
    for (int k = 0; k < 64; k++) {
        const float tv = tok[gg][k];
        const float4* wq4 = (const float4*)&Wqs[k][qq * 16];
        const float4* wk4 = (const float4*)&Wks[k][qq * 16];
        const float4* wv4 = (const float4*)&Wvs[k][qq * 16];
#pragma unroll
        for (int j4 = 0; j4 < 4; j4++) {
            float4 a = wq4[j4], bq = wk4[j4], c = wv4[j4];
            aq[j4*4+0] = fmaf(tv, a.x,  aq[j4*4+0]);
            aq[j4*4+1] = fmaf(tv, a.y,  aq[j4*4+1]);
            aq[j4*4+2] = fmaf(tv, a.z,  aq[j4*4+2]);
            aq[j4*4+3] = fmaf(tv, a.w,  aq[j4*4+3]);
            ak[j4*4+0] = fmaf(tv, bq.x, ak[j4*4+0]);
            ak[j4*4+1] = fmaf(tv, bq.y, ak[j4*4+1]);
            ak[j4*4+2] = fmaf(tv, bq.z, ak[j4*4+2]);
            ak[j4*4+3] = fmaf(tv, bq.w, ak[j4*4+3]);
            av[j4*4+0] = fmaf(tv, c.x,  av[j4*4+0]);
            av[j4*4+1] = fmaf(tv, c.y,  av[j4*4+1]);
            av[j4*4+2] = fmaf(tv, c.z,  av[j4*4+2]);
            av[j4*4+3] = fmaf(tv, c.w,  av[j4*4+3]);
        }
    }
#pragma unroll
    for (int j = 0; j < 16; j++) {
        qS[gg][qq * 16 + j] = aq[j];
        kS[gg][qq * 16 + j] = ak[j];
        vS[gg][qq * 16 + j] = av[j];
    }
    __syncthreads();

    float sc[16] = {};
    for (int d4 = 0; d4 < 16; d4++) {
        float4 q4 = *(const float4*)&qS[gg][d4 * 4];
#pragma unroll
        for (int j = 0; j < 16; j++) {
            float4 k4 = *(const float4*)&kS[qq * 16 + j][d4 * 4];
            sc[j] = fmaf(q4.x, k4.x, sc[j]);
            sc[j] = fmaf(q4.y, k4.y, sc[j]);
            sc[j] = fmaf(q4.z, k4.z, sc[j]);
            sc[j] = fmaf(q4.w, k4.w, sc[j]);
        }
    }
    const float SCALE = 0.125f;
    float mx = -1e30f;
#pragma unroll
    for (int j = 0; j < 16; j++) { sc[j] *= SCALE; mx = fmaxf(mx, sc[j]); }
    mx = fmaxf(mx, __shfl_xor(mx, 1));
    mx = fmaxf(mx, __shfl_xor(mx, 2));
    float s = 0.f;
#pragma unroll
    for (int j = 0; j < 16; j++) { sc[j] = __expf(sc[j] - mx); s += sc[j]; }
    s += __shfl_xor(s, 1);
    s += __shfl_xor(s, 2);
    const float invs = 1.0f / s;
#pragma unroll
    for (int j = 0; j < 16; j++) pS[gg][qq * 16 + j] = sc[j] * invs;
    __syncthreads();

    float oo[16] = {};
    for (int j = 0; j < 64; j++) {
        const float pv = pS[gg][j];
        const float4* v4p = (const float4*)&vS[j][qq * 16];
#pragma unroll
        for (int d4 = 0; d4 < 4; d4++) {
            float4 v4 = v4p[d4];
            oo[d4*4+0] = fmaf(pv, v4.x, oo[d4*4+0]);
            oo[d4*4+1] = fmaf(pv, v4.y, oo[d4*4+1]);
            oo[d4*4+2] = fmaf(pv, v4.z, oo[d4*4+2]);
            oo[d4*4+3] = fmaf(pv, v4.w, oo[d4*4+3]);
        }
    }
    float* op = out_slice + (size_t)bh * 4096 + gg * 64 + qq * 16;
#pragma unroll
    for (int d4 = 0; d4 < 4; d4++) {
        float4 o; o.x = oo[d4*4+0]; o.y = oo[d4*4+1]; o.z = oo[d4*4+2]; o.w = oo[d4*4+3];
        *(float4*)(op + d4 * 4) = o;
    }
}

// ---------------------------------------------------------------------------
// K5: Mt[c][hg] = sum_d os[b][h][g][d] * W_out[h*64+d][c], split hi/lo bf16
// ---------------------------------------------------------------------------
__global__ __launch_bounds__(256) void k_m(
    const float* __restrict__ os, const float* __restrict__ W_out,
    unsigned short* __restrict__ Mt_hi, unsigned short* __restrict__ Mt_lo)
{
    const int h = blockIdx.x, b = blockIdx.y;
    const int t = threadIdx.x;   // c
    __shared__ float osl[64][65];
    for (int i = t; i < 4096; i += 256)
        osl[i >> 6][i & 63] = os[(size_t)(b * 8 + h) * 4096 + i];
    __syncthreads();
    float acc[64];
#pragma unroll
    for (int g = 0; g < 64; g++) acc[g] = 0.f;
    for (int d = 0; d < 64; d++) {
        float wv = W_out[(size_t)(h * 64 + d) * 256 + t];
#pragma unroll
        for (int g = 0; g < 64; g++) acc[g] = fmaf(osl[g][d], wv, acc[g]);
    }
    unsigned short* ph = Mt_hi + (size_t)(b * 256 + t) * 512 + h * 64;
    unsigned short* pl = Mt_lo + (size_t)(b * 256 + t) * 512 + h * 64;
#pragma unroll
    for (int g4 = 0; g4 < 16; g4++) {
        ushort4 uh, ul;
        unsigned short hh; float v, lo;
        v = acc[g4*4+0]; hh = f2bf(v); lo = v - bf2f(hh); uh.x = hh; ul.x = f2bf(lo);
        v = acc[g4*4+1]; hh = f2bf(v); lo = v - bf2f(hh); uh.y = hh; ul.y = f2bf(lo);
        v = acc[g4*4+2]; hh = f2bf(v); lo = v - bf2f(hh); uh.z = hh; ul.z = f2bf(lo);
        v = acc[g4*4+3]; hh = f2bf(v); lo = v - bf2f(hh); uh.w = hh; ul.w = f2bf(lo);
        *(ushort4*)(ph + g4 * 4) = uh;
        *(ushort4*)(pl + g4 * 4) = ul;
    }
}

// ---------------------------------------------------------------------------
// K6: out = wN @ (Mt_hi+Mt_lo)^T + bout  (MFMA, XCD-affinity swizzle:
// both ntiles of an mtile share the wN A-tile -> same XCD)
// ---------------------------------------------------------------------------
__global__ __launch_bounds__(256, 3) void k_out(
    const unsigned short* __restrict__ wN,
    const unsigned short* __restrict__ Mt_hi, const unsigned short* __restrict__ Mt_lo,
    const float* __restrict__ bout, float* __restrict__ out)
{
    __shared__ unsigned short A[128 * 64];
    __shared__ unsigned short Bh[128 * 64];
    __shared__ unsigned short Bl[128 * 64];
    const int L = blockIdx.x;              // 0..2047
    const int xcd = L & 7;
    const int j = L >> 3;                  // 0..255
    const int mtile = xcd * 128 + (j >> 1);
    const int ntile = j & 1;
    const int m0 = mtile * 128, col0 = ntile * 128;
    const int b = m0 >> 15;
    const int t = threadIdx.x;
    const int w = t >> 6, lane = t & 63, l15 = lane & 15, quad = lane >> 4;
    const int wm = w >> 1, wn = w & 1;

    f32x4 acc[4][4];
#pragma unroll
    for (int r = 0; r < 4; r++)
#pragma unroll
        for (int c = 0; c < 4; c++) acc[r][c] = (f32x4){0.f, 0.f, 0.f, 0.f};

    for (int kb = 0; kb < 512; kb += 64) {
        __syncthreads();
#pragma unroll
        for (int rr = 0; rr < 4; rr++) {
            int flat = rr * 256 + t;
            int row = flat >> 3, col = (flat & 7) * 8;
            gll16(wN + (size_t)(m0 + row) * 512 + kb + col, (char*)A + flat * 16);
            gll16(Mt_hi + (size_t)(b * 256 + col0 + row) * 512 + kb + col, (char*)Bh + flat * 16);
            gll16(Mt_lo + (size_t)(b * 256 + col0 + row) * 512 + kb + col, (char*)Bl + flat * 16);
        }
        __syncthreads();
#pragma unroll
        for (int ks = 0; ks < 2; ks++) {
            bf16x8 af[4], bh4[4], bl4[4];
#pragma unroll
            for (int r = 0; r < 4; r++)
                af[r] = *(const bf16x8*)&A[(wm * 64 + r * 16 + l15) * 64 + ks * 32 + quad * 8];
#pragma unroll
            for (int c = 0; c < 4; c++) {
                bh4[c] = *(const bf16x8*)&Bh[(wn * 64 + c * 16 + l15) * 64 + ks * 32 + quad * 8];
                bl4[c] = *(const bf16x8*)&Bl[(wn * 64 + c * 16 + l15) * 64 + ks * 32 + quad * 8];
            }
#pragma unroll
            for (int r = 0; r < 4; r++)
#pragma unroll
                for (int c = 0; c < 4; c++) {
                    acc[r][c] = __builtin_amdgcn_mfma_f32_16x16x32_bf16(af[r], bh4[c], acc[r][c], 0, 0, 0);
                    acc[r][c] = __builtin_amdgcn_mfma_f32_16x16x32_bf16(af[r], bl4[c], acc[r][c], 0, 0, 0);
                }
        }
    }
    float biasc[4];
#pragma unroll
    for (int c = 0; c < 4; c++) biasc[c] = bout[col0 + wn * 64 + c * 16 + l15];
#pragma unroll
    for (int r = 0; r < 4; r++)
#pragma unroll
        for (int c = 0; c < 4; c++)
#pragma unroll
            for (int j2 = 0; j2 < 4; j2++)
                out[(size_t)(m0 + wm * 64 + r * 16 + quad * 4 + j2) * 256 + col0 + wn * 64 + c * 16 + l15] =
                    acc[r][c][j2] + biasc[c];
}

// ---------------------------------------------------------------------------
extern "C" void kernel_launch(void* const* d_in, const int* in_sizes, int n_in,
                              void* d_out, int out_size, void* d_ws, size_t ws_size,
                              hipStream_t stream) {
    const float* x    = (const float*)d_in[0];
    const float* Wfx  = (const float*)d_in[1];
    const float* bfx  = (const float*)d_in[2];
    const float* Wx   = (const float*)d_in[3];
    const float* bx   = (const float*)d_in[4];
    const float* Wsl  = (const float*)d_in[5];
    const float* bsl  = (const float*)d_in[6];
    const float* temp = (const float*)d_in[7];
    const float* Wq   = (const float*)d_in[8];
    const float* Wk   = (const float*)d_in[9];
    const float* Wv   = (const float*)d_in[10];
    const float* Wout = (const float*)d_in[11];
    const float* bout = (const float*)d_in[12];
    float* out = (float*)d_out;

    const int Mtotal = in_sizes[0] / DIM;   // 131072
    const int B = Mtotal / NPTS;            // 4

    // workspace (~138 MB peak)
    char* p = (char*)d_ws;
    unsigned short* Wbt   = (unsigned short*)p; p += (size_t)1024 * 256 * 2;        // 512 KB
    unsigned short* WslTg = (unsigned short*)p; p += (size_t)64 * 64 * 2;           // 8 KB
    unsigned short* wN    = (unsigned short*)p; p += (size_t)Mtotal * INNER * 2;    // 134 MB
    float* token_num = (float*)p; p += (size_t)B * 8 * 64 * 64 * 4;                 // 512 KB
    float* norm_ws   = (float*)p; p += (size_t)B * 8 * 64 * 4;                      // 8 KB
    float* os_ws     = (float*)p; p += (size_t)B * 8 * 64 * 64 * 4;                 // 512 KB
    unsigned short* Mt_hi = (unsigned short*)p; p += (size_t)B * 256 * 512 * 2;     // 1 MB
    unsigned short* Mt_lo = (unsigned short*)p; p += (size_t)B * 256 * 512 * 2;     // 1 MB

    hipMemsetAsync(token_num, 0,
                   (size_t)B * 8 * 64 * 64 * 4 + (size_t)B * 8 * 64 * 4, stream);

    k_prep<<<5, 256, 0, stream>>>(Wfx, Wx, Wsl, Wbt, WslTg);
    k_projfused<<<2048, 256, 0, stream>>>(
        x, Wbt, bfx, bx, WslTg, bsl, temp, wN, token_num, norm_ws);
    k_attn<<<B * 8, 256, 0, stream>>>(token_num, norm_ws, Wq, Wk, Wv, os_ws);
    k_m<<<dim3(8, B), 256, 0, stream>>>(os_ws, Wout, Mt_hi, Mt_lo);
    k_out<<<2048, 256, 0, stream>>>(wN, Mt_hi, Mt_lo, bout, out);
}